// Round 3
// baseline (1351.183 us; speedup 1.0000x reference)
//
#include <hip/hip_runtime.h>
#include <hip/hip_bf16.h>

#define B 8
#define N 2048
#define BN (B*N)
#define KNBR 32
#define NKP 15

__device__ __forceinline__ float lrelu(float x){ return x > 0.f ? x : 0.1f*x; }

// ---------------------------------------------------------------------------
// PointNet: f = relu(relu(x@W1+b1)@W2+b2); also emit masked coords + sq
// block = 256 threads = 4 points x 64 channels
__global__ __launch_bounds__(256) void k_pointnet(
    const float* __restrict__ x, const int* __restrict__ m,
    const float* __restrict__ w1, const float* __restrict__ b1,
    const float* __restrict__ w2, const float* __restrict__ b2,
    float* __restrict__ feat, float* __restrict__ coords, float* __restrict__ sq)
{
    const int lp = threadIdx.x >> 6;
    const int p  = blockIdx.x * 4 + lp;
    const int c  = threadIdx.x & 63;
    const float x0 = x[p*3+0], x1v = x[p*3+1], x2v = x[p*3+2];
    __shared__ float h[4][64];
    float s = b1[c];
    s = fmaf(x0,  w1[0*64+c], s);
    s = fmaf(x1v, w1[1*64+c], s);
    s = fmaf(x2v, w1[2*64+c], s);
    h[lp][c] = fmaxf(s, 0.f);
    __syncthreads();
    float acc = b2[c];
    #pragma unroll 8
    for (int j = 0; j < 64; j++) acc = fmaf(h[lp][j], w2[j*64+c], acc);
    feat[(size_t)p*64 + c] = fmaxf(acc, 0.f);
    if (c == 0) {
        const bool mm = (m[p] != 0);
        const float cx = mm ? 1e6f : x0, cy = mm ? 1e6f : x1v, cz = mm ? 1e6f : x2v;
        coords[p*3+0] = cx; coords[p*3+1] = cy; coords[p*3+2] = cz;
        sq[p] = cx*cx + cy*cy + cz*cz;
    }
}

// ---------------------------------------------------------------------------
// KNN: per-thread top-32 smallest d2 (d2 = sq_n + sq_m - 2*dot, ref formula),
// strict < replacement => neighbor SET matches ref; downstream is
// permutation-invariant in neighbor order.
// block = 64 threads (64 points), grid = 8 batches * 32
__global__ __launch_bounds__(64) void k_knn(
    const float* __restrict__ coords, const float* __restrict__ sq,
    int* __restrict__ idx)
{
    const int b  = blockIdx.x >> 5;            // /32
    const int n  = (blockIdx.x & 31) * 64 + threadIdx.x;
    const int gp = b * N + n;
    const float cx = coords[gp*3+0], cy = coords[gp*3+1], cz = coords[gp*3+2];
    const float sn = sq[gp];

    __shared__ float tx[256], ty[256], tz[256], ts[256];

    float bv[32];
    int   bi[32];
    #pragma unroll
    for (int i = 0; i < 32; i++) { bv[i] = INFINITY; bi[i] = 0; }
    float worst = INFINITY; int wpos = 0;

    for (int t0 = 0; t0 < N; t0 += 256) {
        __syncthreads();
        #pragma unroll
        for (int jj = 0; jj < 4; jj++) {
            const int j = jj*64 + threadIdx.x;
            const int g = b*N + t0 + j;
            tx[j] = coords[g*3+0]; ty[j] = coords[g*3+1]; tz[j] = coords[g*3+2];
            ts[j] = sq[g];
        }
        __syncthreads();
        for (int j = 0; j < 256; j++) {
            const float dot = cx*tx[j] + cy*ty[j] + cz*tz[j];
            const float d2 = sn + ts[j] - 2.f*dot;
            if (d2 < worst) {
                #pragma unroll
                for (int i = 0; i < 32; i++) if (i == wpos) { bv[i] = d2; bi[i] = t0 + j; }
                worst = -INFINITY;
                #pragma unroll
                for (int i = 0; i < 32; i++) if (bv[i] > worst) { worst = bv[i]; wpos = i; }
            }
        }
    }
    #pragma unroll
    for (int i = 0; i < 32; i++) idx[(size_t)gp*KNBR + i] = bi[i];
}

// ---------------------------------------------------------------------------
// x1 = lrelu(feat @ W1) : [BN,CIN] -> [BN,64]
template<int CIN>
__global__ __launch_bounds__(256) void k_unary1(
    const float* __restrict__ feat, const float* __restrict__ w1,
    float* __restrict__ x1)
{
    const int p = blockIdx.x * 4 + (threadIdx.x >> 6);
    const int c = threadIdx.x & 63;
    const float* fp = feat + (size_t)p * CIN;
    float acc = 0.f;
    #pragma unroll 8
    for (int j = 0; j < CIN; j++) acc = fmaf(fp[j], w1[j*64+c], acc);
    x1[(size_t)p*64 + c] = lrelu(acc);
}

// ---------------------------------------------------------------------------
// KPConv core with INLINE kp-weight computation:
// w[K,k] = relu(1 - 2*||(nbr-ctr) - kp_K||)
// agg = sum_k w[K,k]*x1[nbr_k]; x2 = lrelu(agg @ Wk);
// out = lrelu(x2@W2 + feat@Ws).  block = 256, P = 8 points per block.
template<int CIN>
__global__ __launch_bounds__(256) void k_kpconv(
    const float* __restrict__ x1, const float* __restrict__ coords,
    const float* __restrict__ kp,
    const int* __restrict__ idx, const float* __restrict__ feat_in,
    const float* __restrict__ Wk, const float* __restrict__ W2, const float* __restrict__ Ws,
    float* __restrict__ out)
{
    __shared__ float s_w[8*480];
    __shared__ float s_agg[8*960];
    __shared__ float s_x2[8*64];
    __shared__ int   s_idx[256];
    __shared__ float skp[48];
    const int tid   = threadIdx.x;
    const int pbase = blockIdx.x * 8;
    const int brow  = (pbase / N) * N;

    if (tid < NKP*3) skp[tid] = kp[tid];
    s_idx[tid] = idx[(size_t)pbase*KNBR + tid];
    __syncthreads();

    // phase 0: inline kernel-point weights (tid -> pl=tid>>5, k=tid&31)
    {
        const int pl = tid >> 5, k = tid & 31;
        const int p  = pbase + pl;
        const int gn = brow + s_idx[pl*KNBR + k];
        const float dx = coords[gn*3+0] - coords[p*3+0];
        const float dy = coords[gn*3+1] - coords[p*3+1];
        const float dz = coords[gn*3+2] - coords[p*3+2];
        #pragma unroll
        for (int K = 0; K < NKP; K++) {
            const float ex = dx - skp[K*3+0], ey = dy - skp[K*3+1], ez = dz - skp[K*3+2];
            const float dist = sqrtf(ex*ex + ey*ey + ez*ez);
            s_w[pl*480 + K*32 + k] = fmaxf(0.f, 1.f - dist*2.f);
        }
    }
    __syncthreads();

    const int g = tid >> 6, c = tid & 63;
    // phase 1: aggregate neighbors (2 points per thread-group)
    for (int sub = 0; sub < 2; sub++) {
        const int pl = g*2 + sub;
        float ag[NKP];
        #pragma unroll
        for (int K = 0; K < NKP; K++) ag[K] = 0.f;
        const float* wp = &s_w[pl*480];
        for (int k = 0; k < KNBR; k++) {
            const int nb = s_idx[pl*KNBR + k];
            const float val = x1[(size_t)(brow + nb)*64 + c];
            #pragma unroll
            for (int K = 0; K < NKP; K++) ag[K] = fmaf(wp[K*32 + k], val, ag[K]);
        }
        #pragma unroll
        for (int K = 0; K < NKP; K++) s_agg[pl*960 + K*64 + c] = ag[K];
    }
    __syncthreads();

    // phase 2: x2[pl][c] = lrelu(sum_j agg[pl][j] * Wk[j][c]), j = K*64+cin
    {
        float s0 = 0.f, s1 = 0.f;
        const float* a0 = &s_agg[(g*2+0)*960];
        const float* a1 = &s_agg[(g*2+1)*960];
        for (int j = 0; j < 960; j++) {
            const float wv = Wk[(size_t)j*64 + c];   // global, L2-resident
            s0 = fmaf(a0[j], wv, s0);
            s1 = fmaf(a1[j], wv, s1);
        }
        s_x2[(g*2+0)*64 + c] = lrelu(s0);
        s_x2[(g*2+1)*64 + c] = lrelu(s1);
    }
    __syncthreads();

    // phase 3: out = lrelu(x2@W2 + feat@Ws), 128 outputs per point
    {
        const int o = tid & 127, ph = tid >> 7;
        for (int pi = 0; pi < 4; pi++) {
            const int pl = ph*4 + pi;
            const int pg = pbase + pl;
            float acc = 0.f;
            const float* xp = &s_x2[pl*64];
            #pragma unroll 8
            for (int cc = 0; cc < 64; cc++) acc = fmaf(xp[cc], W2[cc*128 + o], acc);
            const float* fp = &feat_in[(size_t)pg*CIN];
            #pragma unroll 8
            for (int j = 0; j < CIN; j++) acc = fmaf(fp[j], Ws[j*128 + o], acc);
            out[(size_t)pg*128 + o] = lrelu(acc);
        }
    }
}

// ---------------------------------------------------------------------------
// VLAD assignment: a = softmax(f @ wa) * valid.  block = 256 = 4 points x 64
__global__ __launch_bounds__(256) void k_vlad_a(
    const float* __restrict__ f, const float* __restrict__ wa,
    const int* __restrict__ m, float* __restrict__ a)
{
    const int p  = blockIdx.x * 4 + (threadIdx.x >> 6);
    const int kc = threadIdx.x & 63;
    const float* fp = f + (size_t)p*128;
    float l = 0.f;
    #pragma unroll 8
    for (int c = 0; c < 128; c++) l = fmaf(fp[c], wa[c*64 + kc], l);
    float mx = l;
    #pragma unroll
    for (int off = 32; off > 0; off >>= 1) mx = fmaxf(mx, __shfl_xor(mx, off, 64));
    const float e = expf(l - mx);
    float se = e;
    #pragma unroll
    for (int off = 32; off > 0; off >>= 1) se += __shfl_xor(se, off, 64);
    const float valid = (m[p] != 0) ? 0.f : 1.f;
    a[(size_t)p*64 + kc] = (e / se) * valid;
}

// ---------------------------------------------------------------------------
// v[b,kc,:] = intra-normalize( sum_n a[b,n,kc]*f[b,n,:] - suma*centers[kc,:] )
// grid = B*64 blocks, 128 threads
__global__ __launch_bounds__(128) void k_vlad_v(
    const float* __restrict__ a, const float* __restrict__ f,
    const float* __restrict__ centers, float* __restrict__ v)
{
    const int b = blockIdx.x >> 6, kc = blockIdx.x & 63, d = threadIdx.x;
    const float* ab = a + (size_t)b*N*64 + kc;
    const float* fb = f + (size_t)b*N*128 + d;
    float acc = 0.f, sa = 0.f;
    for (int n = 0; n < N; n++) {
        const float av = ab[(size_t)n*64];
        acc = fmaf(av, fb[(size_t)n*128], acc);
        sa += av;
    }
    const float vv = acc - sa * centers[kc*128 + d];
    float s2 = vv*vv;
    #pragma unroll
    for (int off = 32; off > 0; off >>= 1) s2 += __shfl_xor(s2, off, 64);
    __shared__ float red[2];
    if ((d & 63) == 0) red[d >> 6] = s2;
    __syncthreads();
    const float tot = red[0] + red[1];
    v[((size_t)b*64 + kc)*128 + d] = vv / (sqrtf(tot) + 1e-8f);
}

// global-norm scale per batch: scale[b] = 1/(||v_b||+1e-8)
__global__ __launch_bounds__(256) void k_vnorm(
    const float* __restrict__ v, float* __restrict__ scale)
{
    const int b = blockIdx.x;
    float s = 0.f;
    for (int i = threadIdx.x; i < 8192; i += 256) { const float t = v[(size_t)b*8192 + i]; s = fmaf(t, t, s); }
    #pragma unroll
    for (int off = 32; off > 0; off >>= 1) s += __shfl_xor(s, off, 64);
    __shared__ float red[4];
    if ((threadIdx.x & 63) == 0) red[threadIdx.x >> 6] = s;
    __syncthreads();
    if (threadIdx.x == 0) {
        const float tot = red[0] + red[1] + red[2] + red[3];
        scale[b] = 1.f / (sqrtf(tot) + 1e-8f);
    }
}

// zero the projection accumulator (avoid hipMemsetAsync entirely)
__global__ __launch_bounds__(256) void k_zero(float* __restrict__ p, int n)
{
    const int i = blockIdx.x * 256 + threadIdx.x;
    if (i < n) p[i] = 0.f;
}

// partial projection: outacc[b,o] += scale[b] * sum_{j in chunk} v[b,j]*proj[j,o]
__global__ __launch_bounds__(256) void k_proj(
    const float* __restrict__ v, const float* __restrict__ scale,
    const float* __restrict__ proj, float* __restrict__ outacc)
{
    const int b = blockIdx.x >> 5, jc = blockIdx.x & 31, o = threadIdx.x;
    const int j0 = jc * 256;
    const float* vb = v + (size_t)b*8192 + j0;
    float acc = 0.f;
    #pragma unroll 4
    for (int jj = 0; jj < 256; jj++) acc = fmaf(vb[jj], proj[(size_t)(j0+jj)*256 + o], acc);
    atomicAdd(&outacc[b*256 + o], acc * scale[b]);
}

// final L2 normalize + f32 store (reference output dtype is float32)
__global__ __launch_bounds__(256) void k_outnorm(
    const float* __restrict__ outacc, float* __restrict__ out)
{
    const int b = blockIdx.x, o = threadIdx.x;
    const float val = outacc[b*256 + o];
    float s = val*val;
    #pragma unroll
    for (int off = 32; off > 0; off >>= 1) s += __shfl_xor(s, off, 64);
    __shared__ float red[4];
    if ((o & 63) == 0) red[o >> 6] = s;
    __syncthreads();
    const float tot = red[0] + red[1] + red[2] + red[3];
    out[b*256 + o] = val / (sqrtf(tot) + 1e-12f);
}

// ---------------------------------------------------------------------------
extern "C" void kernel_launch(void* const* d_in, const int* in_sizes, int n_in,
                              void* d_out, int out_size, void* d_ws, size_t ws_size,
                              hipStream_t stream)
{
    (void)in_sizes; (void)n_in; (void)out_size; (void)ws_size;
    const float* x     = (const float*)d_in[0];
    const int*   m     = (const int*)  d_in[1];
    const float* pn_w1 = (const float*)d_in[2];
    const float* pn_b1 = (const float*)d_in[3];
    const float* pn_w2 = (const float*)d_in[4];
    const float* pn_b2 = (const float*)d_in[5];
    const float* kp    = (const float*)d_in[6];
    const float* bw1[3] = {(const float*)d_in[7],  (const float*)d_in[11], (const float*)d_in[15]};
    const float* bwk[3] = {(const float*)d_in[8],  (const float*)d_in[12], (const float*)d_in[16]};
    const float* bw2[3] = {(const float*)d_in[9],  (const float*)d_in[13], (const float*)d_in[17]};
    const float* bws[3] = {(const float*)d_in[10], (const float*)d_in[14], (const float*)d_in[18]};
    const float* vlad_wa      = (const float*)d_in[19];
    const float* vlad_centers = (const float*)d_in[20];
    const float* vlad_proj    = (const float*)d_in[21];
    float* out = (float*)d_out;

    // Workspace plan (~28.0 MB total):
    char* ws = (char*)d_ws;
    size_t off = 0;
    auto alloc = [&](size_t bytes) -> void* {
        void* p = ws + off;
        off = (off + bytes + 255) & ~(size_t)255;
        return p;
    };
    float* coords = (float*)alloc((size_t)BN*3*4);        //   0.20 MB
    float* sqb    = (float*)alloc((size_t)BN*4);          //   0.07 MB
    float* feat0  = (float*)alloc((size_t)BN*64*4);       //   4.19 MB
    int*   idxb   = (int*)  alloc((size_t)BN*KNBR*4);     //   2.10 MB
    float* x1b    = (float*)alloc((size_t)BN*64*4);       //   4.19 MB
    float* fA     = (float*)alloc((size_t)BN*128*4);      //   8.39 MB
    float* fB     = (float*)alloc((size_t)BN*128*4);      //   8.39 MB
    float* abuf   = (float*)alloc((size_t)BN*64*4);       //   4.19 MB
    float* vbuf   = (float*)alloc((size_t)B*8192*4);      //   0.26 MB
    float* scaleb = (float*)alloc((size_t)B*4);
    float* outacc = (float*)alloc((size_t)B*256*4);

    k_pointnet<<<BN/4, 256, 0, stream>>>(x, m, pn_w1, pn_b1, pn_w2, pn_b2, feat0, coords, sqb);
    k_knn<<<B*32, 64, 0, stream>>>(coords, sqb, idxb);

    k_unary1<64> <<<BN/4, 256, 0, stream>>>(feat0, bw1[0], x1b);
    k_kpconv<64> <<<BN/8, 256, 0, stream>>>(x1b, coords, kp, idxb, feat0, bwk[0], bw2[0], bws[0], fA);
    k_unary1<128><<<BN/4, 256, 0, stream>>>(fA, bw1[1], x1b);
    k_kpconv<128><<<BN/8, 256, 0, stream>>>(x1b, coords, kp, idxb, fA, bwk[1], bw2[1], bws[1], fB);
    k_unary1<128><<<BN/4, 256, 0, stream>>>(fB, bw1[2], x1b);
    k_kpconv<128><<<BN/8, 256, 0, stream>>>(x1b, coords, kp, idxb, fB, bwk[2], bw2[2], bws[2], fA);

    k_vlad_a<<<BN/4, 256, 0, stream>>>(fA, vlad_wa, m, abuf);
    k_vlad_v<<<B*64, 128, 0, stream>>>(abuf, fA, vlad_centers, vbuf);
    k_vnorm<<<B, 256, 0, stream>>>(vbuf, scaleb);
    k_zero<<<(B*256 + 255)/256, 256, 0, stream>>>(outacc, B*256);
    k_proj<<<B*32, 256, 0, stream>>>(vbuf, scaleb, vlad_proj, outacc);
    k_outnorm<<<B, 256, 0, stream>>>(outacc, out);
}

// Round 4
// 865.921 us; speedup vs baseline: 1.5604x; 1.5604x over previous
//
#include <hip/hip_runtime.h>
#include <hip/hip_bf16.h>

#define B 8
#define N 2048
#define BN (B*N)
#define KNBR 32
#define NKP 15

__device__ __forceinline__ float lrelu(float x){ return x > 0.f ? x : 0.1f*x; }

// ---------------------------------------------------------------------------
// PointNet: f = relu(relu(x@W1+b1)@W2+b2); emits coords4 = (masked xyz, sq).
// block = 256 threads = 32 points; each wave handles 8 points (weight-reuse).
__global__ __launch_bounds__(256) void k_pointnet(
    const float* __restrict__ x, const int* __restrict__ m,
    const float* __restrict__ w1, const float* __restrict__ b1,
    const float* __restrict__ w2, const float* __restrict__ b2,
    float* __restrict__ feat, float4* __restrict__ coords4)
{
    __shared__ float s_x[32][3];
    __shared__ float s_hT[64*37 + 8];   // transposed hidden, pad 37 (gcd(37,32)=1)
    const int tid = threadIdx.x;
    const int pbase = blockIdx.x * 32;
    if (tid < 32) {
        const int p = pbase + tid;
        const float x0 = x[p*3+0], x1v = x[p*3+1], x2v = x[p*3+2];
        s_x[tid][0] = x0; s_x[tid][1] = x1v; s_x[tid][2] = x2v;
        const bool mm = (m[p] != 0);
        const float cx = mm ? 1e6f : x0, cy = mm ? 1e6f : x1v, cz = mm ? 1e6f : x2v;
        coords4[p] = make_float4(cx, cy, cz, cx*cx + cy*cy + cz*cz);
    }
    __syncthreads();
    const int w = tid >> 6, c = tid & 63;
    const int pb = w * 8;
    // hidden layer
    {
        const float w10 = w1[c], w11 = w1[64+c], w12 = w1[128+c], bb = b1[c];
        #pragma unroll
        for (int pl = 0; pl < 8; pl++) {
            float s = bb;
            s = fmaf(s_x[pb+pl][0], w10, s);
            s = fmaf(s_x[pb+pl][1], w11, s);
            s = fmaf(s_x[pb+pl][2], w12, s);
            s_hT[c*37 + pb + pl] = fmaxf(s, 0.f);   // same-wave LDS: no barrier needed
        }
    }
    // output layer (each wave reads w2 once for its 8 points)
    {
        float acc[8];
        const float bb = b2[c];
        #pragma unroll
        for (int pl = 0; pl < 8; pl++) acc[pl] = bb;
        for (int j = 0; j < 64; j++) {
            const float wv = w2[j*64 + c];
            const float* hr = &s_hT[j*37 + pb];
            #pragma unroll
            for (int pl = 0; pl < 8; pl++) acc[pl] = fmaf(hr[pl], wv, acc[pl]);
        }
        #pragma unroll
        for (int pl = 0; pl < 8; pl++)
            feat[(size_t)(pbase + pb + pl)*64 + c] = fmaxf(acc[pl], 0.f);
    }
}

// ---------------------------------------------------------------------------
// KNN via wave-per-point bitonic top-64 (superset of top-32), branch-free.
// Candidate packed as uint: (d2 bits & ~0x7FF) | idx(11b). d2 clamped >= 0 so
// uint order == float order. Tie-perturbation (2^-11 relative) only reorders
// near-equal d2 pairs, which carry ~zero KP weight or are masked.
// block = 256 = 4 point-waves; one shared LDS stage of all 2048 candidates.
__global__ __launch_bounds__(256) void k_knn(
    const float4* __restrict__ c4, int* __restrict__ idx)
{
    __shared__ float4 s_c[N];
    const int tid = threadIdx.x;
    const int w = tid >> 6, lane = tid & 63;
    const int p = blockIdx.x * 4 + w;
    const int b = p >> 11;
    for (int i = tid; i < N; i += 256) s_c[i] = c4[(size_t)b*N + i];
    __syncthreads();
    const float4 me = s_c[p & (N-1)];
    unsigned top = 0x7F800000u;          // +inf pattern, replaced after batch 0
    for (int t0 = 0; t0 < N; t0 += 64) {
        const float4 s = s_c[t0 + lane];
        float d2 = me.w + s.w - 2.f*(me.x*s.x + me.y*s.y + me.z*s.z);
        d2 = fmaxf(d2, 0.f);
        unsigned v = (__float_as_uint(d2) & 0xFFFFF800u) | (unsigned)(t0 + lane);
        // bitonic sort 64 ascending across lanes
        #pragma unroll
        for (int k = 2; k <= 64; k <<= 1) {
            #pragma unroll
            for (int j = k >> 1; j > 0; j >>= 1) {
                const unsigned pv = (unsigned)__shfl_xor((int)v, j, 64);
                const unsigned lo = v < pv ? v : pv;
                const unsigned hi = v < pv ? pv : v;
                v = (((lane & k) == 0) == ((lane & j) == 0)) ? lo : hi;
            }
        }
        // merge sorted top (asc) with sorted batch (asc, reversed -> desc):
        const unsigned rb = (unsigned)__shfl((int)v, 63 - lane, 64);
        unsigned mm = top < rb ? top : rb;       // lower-64, bitonic
        #pragma unroll
        for (int j = 32; j > 0; j >>= 1) {
            const unsigned pv = (unsigned)__shfl_xor((int)mm, j, 64);
            const unsigned lo = mm < pv ? mm : pv;
            const unsigned hi = mm < pv ? pv : mm;
            mm = ((lane & j) == 0) ? lo : hi;
        }
        top = mm;
    }
    if (lane < 32) idx[(size_t)p*KNBR + lane] = (int)(top & 0x7FFu);
}

// ---------------------------------------------------------------------------
// x1 = lrelu(feat @ W1) : [BN,CIN] -> [BN,64].
// block = 256 = 32 points; wave handles 8 points; feat staged transposed.
template<int CIN>
__global__ __launch_bounds__(256) void k_unary1(
    const float* __restrict__ feat, const float* __restrict__ w1,
    float* __restrict__ x1)
{
    __shared__ float s_fT[128*36 + 8];
    const int tid = threadIdx.x;
    const int pbase = blockIdx.x * 32;
    for (int i = tid; i < 32*CIN; i += 256) {
        const int p = i / CIN, j = i % CIN;
        s_fT[j*36 + p] = feat[(size_t)pbase*CIN + i];
    }
    __syncthreads();
    const int w = tid >> 6, c = tid & 63;
    const int pb = w * 8;
    float acc[8] = {0.f,0.f,0.f,0.f,0.f,0.f,0.f,0.f};
    for (int j = 0; j < CIN; j++) {
        const float wv = w1[j*64 + c];
        const float* fr = &s_fT[j*36 + pb];
        #pragma unroll
        for (int pl = 0; pl < 8; pl++) acc[pl] = fmaf(fr[pl], wv, acc[pl]);
    }
    #pragma unroll
    for (int pl = 0; pl < 8; pl++)
        x1[(size_t)(pbase + pb + pl)*64 + c] = lrelu(acc[pl]);
}

// ---------------------------------------------------------------------------
// KPConv: inline kp-weights; agg; x2 = lrelu(agg@Wk); out = lrelu(x2@W2+feat@Ws)
// block = 256, 8 points. Phase 2 split-K across 4 waves (Wk read ONCE/block);
// phase 3 split-O across 4 waves (W2/Ws read ~once/block, L1 reuse).
template<int CIN>
__global__ __launch_bounds__(256) void k_kpconv(
    const float* __restrict__ x1, const float4* __restrict__ c4,
    const float* __restrict__ kp,
    const int* __restrict__ idx, const float* __restrict__ feat_in,
    const float* __restrict__ Wk, const float* __restrict__ W2, const float* __restrict__ Ws,
    float* __restrict__ out)
{
    __shared__ float s_w[8*480];        // kp weights; aliased as s_part in ph2
    __shared__ float s_aggT[960*9];     // transposed agg, pad 9 (conflict-free)
    __shared__ float s_x2[8*64];
    __shared__ float s_feat[8*128];
    __shared__ int   s_idx[256];
    __shared__ float skp[48];
    const int tid   = threadIdx.x;
    const int pbase = blockIdx.x * 8;
    const int brow  = (pbase / N) * N;

    if (tid < NKP*3) skp[tid] = kp[tid];
    s_idx[tid] = idx[(size_t)pbase*KNBR + tid];
    for (int i = tid; i < 8*CIN; i += 256) s_feat[i] = feat_in[(size_t)pbase*CIN + i];
    __syncthreads();

    // phase 0: kp influence weights (tid -> pl=tid>>5, k=tid&31)
    {
        const int pl = tid >> 5, k = tid & 31;
        const float4 cp = c4[pbase + pl];
        const float4 cn = c4[brow + s_idx[pl*KNBR + k]];
        const float dx = cn.x - cp.x, dy = cn.y - cp.y, dz = cn.z - cp.z;
        #pragma unroll
        for (int K = 0; K < NKP; K++) {
            const float ex = dx - skp[K*3+0], ey = dy - skp[K*3+1], ez = dz - skp[K*3+2];
            const float dist = sqrtf(ex*ex + ey*ey + ez*ez);
            s_w[pl*480 + K*32 + k] = fmaxf(0.f, 1.f - dist*2.f);
        }
    }
    __syncthreads();

    const int w = tid >> 6, lane = tid & 63;
    // phase 1: neighbor aggregation (wave w -> points 2w, 2w+1; lane = channel)
    #pragma unroll
    for (int sub = 0; sub < 2; sub++) {
        const int pl = w*2 + sub;
        float ag[NKP];
        #pragma unroll
        for (int K = 0; K < NKP; K++) ag[K] = 0.f;
        const float* wp = &s_w[pl*480];
        for (int k = 0; k < KNBR; k++) {
            const float val = x1[(size_t)(brow + s_idx[pl*KNBR + k])*64 + lane];
            #pragma unroll
            for (int K = 0; K < NKP; K++) ag[K] = fmaf(wp[K*32 + k], val, ag[K]);
        }
        #pragma unroll
        for (int K = 0; K < NKP; K++) s_aggT[(K*64 + lane)*9 + pl] = ag[K];
    }
    __syncthreads();

    // phase 2: x2 = lrelu(agg @ Wk), split-K: wave w handles j in [240w,240w+240)
    {
        float acc[8] = {0.f,0.f,0.f,0.f,0.f,0.f,0.f,0.f};
        const int jlo = w * 240, jhi = jlo + 240;
        #pragma unroll 4
        for (int j = jlo; j < jhi; j++) {
            const float wv = Wk[(size_t)j*64 + lane];
            const float* ar = &s_aggT[j*9];
            #pragma unroll
            for (int pl = 0; pl < 8; pl++) acc[pl] = fmaf(ar[pl], wv, acc[pl]);
        }
        float* s_part = s_w;            // alias: s_w dead after phase 1
        #pragma unroll
        for (int pl = 0; pl < 8; pl++) s_part[w*512 + pl*64 + lane] = acc[pl];
    }
    __syncthreads();
    {
        const float* s_part = s_w;
        for (int i = tid; i < 512; i += 256)
            s_x2[i] = lrelu(s_part[i] + s_part[512+i] + s_part[1024+i] + s_part[1536+i]);
    }
    __syncthreads();

    // phase 3: out = lrelu(x2@W2 + feat@Ws), split-O: wave w -> o in [32w,32w+32)
    {
        const int o = (w << 5) + (lane & 31);
        const int h = lane >> 5;
        #pragma unroll
        for (int pi = 0; pi < 4; pi++) {
            const int pl = h*4 + pi;
            float acc = 0.f;
            const float* xp = &s_x2[pl*64];
            #pragma unroll 8
            for (int cc = 0; cc < 64; cc++) acc = fmaf(xp[cc], W2[cc*128 + o], acc);
            const float* fp = &s_feat[pl*CIN];
            #pragma unroll 8
            for (int j = 0; j < CIN; j++) acc = fmaf(fp[j], Ws[j*128 + o], acc);
            out[(size_t)(pbase + pl)*128 + o] = lrelu(acc);
        }
    }
}

// ---------------------------------------------------------------------------
// VLAD assignment: a = softmax(f @ wa) * valid. 32 points/block, 8/wave.
__global__ __launch_bounds__(256) void k_vlad_a(
    const float* __restrict__ f, const float* __restrict__ wa,
    const int* __restrict__ m, float* __restrict__ a)
{
    __shared__ float s_fT[128*36 + 8];
    __shared__ float s_m[32];
    const int tid = threadIdx.x;
    const int pbase = blockIdx.x * 32;
    for (int i = tid; i < 32*128; i += 256) {
        const int p = i >> 7, j = i & 127;
        s_fT[j*36 + p] = f[(size_t)pbase*128 + i];
    }
    if (tid < 32) s_m[tid] = (m[pbase + tid] != 0) ? 0.f : 1.f;
    __syncthreads();
    const int w = tid >> 6, kc = tid & 63;
    const int pb = w * 8;
    float acc[8] = {0.f,0.f,0.f,0.f,0.f,0.f,0.f,0.f};
    for (int j = 0; j < 128; j++) {
        const float wv = wa[j*64 + kc];
        const float* fr = &s_fT[j*36 + pb];
        #pragma unroll
        for (int pl = 0; pl < 8; pl++) acc[pl] = fmaf(fr[pl], wv, acc[pl]);
    }
    #pragma unroll
    for (int pl = 0; pl < 8; pl++) {
        float mx = acc[pl];
        #pragma unroll
        for (int off = 32; off > 0; off >>= 1) mx = fmaxf(mx, __shfl_xor(mx, off, 64));
        const float e = expf(acc[pl] - mx);
        float se = e;
        #pragma unroll
        for (int off = 32; off > 0; off >>= 1) se += __shfl_xor(se, off, 64);
        a[(size_t)(pbase + pb + pl)*64 + kc] = (e / se) * s_m[pb + pl];
    }
}

// ---------------------------------------------------------------------------
// v[b,kc,:] = intra-normalize( sum_n a[b,n,kc]*f[b,n,:] - suma*centers[kc,:] )
__global__ __launch_bounds__(128) void k_vlad_v(
    const float* __restrict__ a, const float* __restrict__ f,
    const float* __restrict__ centers, float* __restrict__ v)
{
    const int b = blockIdx.x >> 6, kc = blockIdx.x & 63, d = threadIdx.x;
    const float* ab = a + (size_t)b*N*64 + kc;
    const float* fb = f + (size_t)b*N*128 + d;
    float acc = 0.f, sa = 0.f;
    for (int n = 0; n < N; n++) {
        const float av = ab[(size_t)n*64];
        acc = fmaf(av, fb[(size_t)n*128], acc);
        sa += av;
    }
    const float vv = acc - sa * centers[kc*128 + d];
    float s2 = vv*vv;
    #pragma unroll
    for (int off = 32; off > 0; off >>= 1) s2 += __shfl_xor(s2, off, 64);
    __shared__ float red[2];
    if ((d & 63) == 0) red[d >> 6] = s2;
    __syncthreads();
    const float tot = red[0] + red[1];
    v[((size_t)b*64 + kc)*128 + d] = vv / (sqrtf(tot) + 1e-8f);
}

// global-norm scale per batch: scale[b] = 1/(||v_b||+1e-8)
__global__ __launch_bounds__(256) void k_vnorm(
    const float* __restrict__ v, float* __restrict__ scale)
{
    const int b = blockIdx.x;
    float s = 0.f;
    for (int i = threadIdx.x; i < 8192; i += 256) { const float t = v[(size_t)b*8192 + i]; s = fmaf(t, t, s); }
    #pragma unroll
    for (int off = 32; off > 0; off >>= 1) s += __shfl_xor(s, off, 64);
    __shared__ float red[4];
    if ((threadIdx.x & 63) == 0) red[threadIdx.x >> 6] = s;
    __syncthreads();
    if (threadIdx.x == 0) {
        const float tot = red[0] + red[1] + red[2] + red[3];
        scale[b] = 1.f / (sqrtf(tot) + 1e-8f);
    }
}

__global__ __launch_bounds__(256) void k_zero(float* __restrict__ p, int n)
{
    const int i = blockIdx.x * 256 + threadIdx.x;
    if (i < n) p[i] = 0.f;
}

// partial projection: outacc[b,o] += scale[b] * sum_{j in chunk} v[b,j]*proj[j,o]
__global__ __launch_bounds__(256) void k_proj(
    const float* __restrict__ v, const float* __restrict__ scale,
    const float* __restrict__ proj, float* __restrict__ outacc)
{
    const int b = blockIdx.x >> 5, jc = blockIdx.x & 31, o = threadIdx.x;
    const int j0 = jc * 256;
    const float* vb = v + (size_t)b*8192 + j0;
    float acc = 0.f;
    #pragma unroll 4
    for (int jj = 0; jj < 256; jj++) acc = fmaf(vb[jj], proj[(size_t)(j0+jj)*256 + o], acc);
    atomicAdd(&outacc[b*256 + o], acc * scale[b]);
}

// final L2 normalize + f32 store
__global__ __launch_bounds__(256) void k_outnorm(
    const float* __restrict__ outacc, float* __restrict__ out)
{
    const int b = blockIdx.x, o = threadIdx.x;
    const float val = outacc[b*256 + o];
    float s = val*val;
    #pragma unroll
    for (int off = 32; off > 0; off >>= 1) s += __shfl_xor(s, off, 64);
    __shared__ float red[4];
    if ((o & 63) == 0) red[o >> 6] = s;
    __syncthreads();
    const float tot = red[0] + red[1] + red[2] + red[3];
    out[b*256 + o] = val / (sqrtf(tot) + 1e-12f);
}

// ---------------------------------------------------------------------------
extern "C" void kernel_launch(void* const* d_in, const int* in_sizes, int n_in,
                              void* d_out, int out_size, void* d_ws, size_t ws_size,
                              hipStream_t stream)
{
    (void)in_sizes; (void)n_in; (void)out_size; (void)ws_size;
    const float* x     = (const float*)d_in[0];
    const int*   m     = (const int*)  d_in[1];
    const float* pn_w1 = (const float*)d_in[2];
    const float* pn_b1 = (const float*)d_in[3];
    const float* pn_w2 = (const float*)d_in[4];
    const float* pn_b2 = (const float*)d_in[5];
    const float* kp    = (const float*)d_in[6];
    const float* bw1[3] = {(const float*)d_in[7],  (const float*)d_in[11], (const float*)d_in[15]};
    const float* bwk[3] = {(const float*)d_in[8],  (const float*)d_in[12], (const float*)d_in[16]};
    const float* bw2[3] = {(const float*)d_in[9],  (const float*)d_in[13], (const float*)d_in[17]};
    const float* bws[3] = {(const float*)d_in[10], (const float*)d_in[14], (const float*)d_in[18]};
    const float* vlad_wa      = (const float*)d_in[19];
    const float* vlad_centers = (const float*)d_in[20];
    const float* vlad_proj    = (const float*)d_in[21];
    float* out = (float*)d_out;

    char* ws = (char*)d_ws;
    size_t off = 0;
    auto alloc = [&](size_t bytes) -> void* {
        void* p = ws + off;
        off = (off + bytes + 255) & ~(size_t)255;
        return p;
    };
    float4* coords4 = (float4*)alloc((size_t)BN*16);      //  0.26 MB
    float*  feat0   = (float*)alloc((size_t)BN*64*4);     //  4.19 MB
    int*    idxb    = (int*)  alloc((size_t)BN*KNBR*4);   //  2.10 MB
    float*  x1b     = (float*)alloc((size_t)BN*64*4);     //  4.19 MB
    float*  fA      = (float*)alloc((size_t)BN*128*4);    //  8.39 MB
    float*  fB      = (float*)alloc((size_t)BN*128*4);    //  8.39 MB
    float*  abuf    = (float*)alloc((size_t)BN*64*4);     //  4.19 MB
    float*  vbuf    = (float*)alloc((size_t)B*8192*4);    //  0.26 MB
    float*  scaleb  = (float*)alloc((size_t)B*4);
    float*  outacc  = (float*)alloc((size_t)B*256*4);

    k_pointnet<<<BN/32, 256, 0, stream>>>(x, m, pn_w1, pn_b1, pn_w2, pn_b2, feat0, coords4);
    k_knn<<<BN/4, 256, 0, stream>>>(coords4, idxb);

    k_unary1<64> <<<BN/32, 256, 0, stream>>>(feat0, bw1[0], x1b);
    k_kpconv<64> <<<BN/8, 256, 0, stream>>>(x1b, coords4, kp, idxb, feat0, bwk[0], bw2[0], bws[0], fA);
    k_unary1<128><<<BN/32, 256, 0, stream>>>(fA, bw1[1], x1b);
    k_kpconv<128><<<BN/8, 256, 0, stream>>>(x1b, coords4, kp, idxb, fA, bwk[1], bw2[1], bws[1], fB);
    k_unary1<128><<<BN/32, 256, 0, stream>>>(fB, bw1[2], x1b);
    k_kpconv<128><<<BN/8, 256, 0, stream>>>(x1b, coords4, kp, idxb, fB, bwk[2], bw2[2], bws[2], fA);

    k_vlad_a<<<BN/32, 256, 0, stream>>>(fA, vlad_wa, m, abuf);
    k_vlad_v<<<B*64, 128, 0, stream>>>(abuf, fA, vlad_centers, vbuf);
    k_vnorm<<<B, 256, 0, stream>>>(vbuf, scaleb);
    k_zero<<<(B*256 + 255)/256, 256, 0, stream>>>(outacc, B*256);
    k_proj<<<B*32, 256, 0, stream>>>(vbuf, scaleb, vlad_proj, outacc);
    k_outnorm<<<B, 256, 0, stream>>>(outacc, out);
}

// Round 5
// 700.910 us; speedup vs baseline: 1.9278x; 1.2354x over previous
//
#include <hip/hip_runtime.h>
#include <hip/hip_bf16.h>

#define B 8
#define N 2048
#define BN (B*N)
#define KNBR 32
#define NKP 15
#define VCH 16   // n-chunks per batch in VLAD accumulation

__device__ __forceinline__ float lrelu(float x){ return x > 0.f ? x : 0.1f*x; }

// ---------------------------------------------------------------------------
// PointNet: f = relu(relu(x@W1+b1)@W2+b2); emits coords4 = (masked xyz, sq).
// block = 256 threads = 32 points; each wave handles 8 points (weight-reuse).
__global__ __launch_bounds__(256) void k_pointnet(
    const float* __restrict__ x, const int* __restrict__ m,
    const float* __restrict__ w1, const float* __restrict__ b1,
    const float* __restrict__ w2, const float* __restrict__ b2,
    float* __restrict__ feat, float4* __restrict__ coords4)
{
    __shared__ float s_x[32][3];
    __shared__ float s_hT[64*37 + 8];   // transposed hidden, pad 37 (gcd(37,32)=1)
    const int tid = threadIdx.x;
    const int pbase = blockIdx.x * 32;
    if (tid < 32) {
        const int p = pbase + tid;
        const float x0 = x[p*3+0], x1v = x[p*3+1], x2v = x[p*3+2];
        s_x[tid][0] = x0; s_x[tid][1] = x1v; s_x[tid][2] = x2v;
        const bool mm = (m[p] != 0);
        const float cx = mm ? 1e6f : x0, cy = mm ? 1e6f : x1v, cz = mm ? 1e6f : x2v;
        coords4[p] = make_float4(cx, cy, cz, cx*cx + cy*cy + cz*cz);
    }
    __syncthreads();
    const int w = tid >> 6, c = tid & 63;
    const int pb = w * 8;
    {
        const float w10 = w1[c], w11 = w1[64+c], w12 = w1[128+c], bb = b1[c];
        #pragma unroll
        for (int pl = 0; pl < 8; pl++) {
            float s = bb;
            s = fmaf(s_x[pb+pl][0], w10, s);
            s = fmaf(s_x[pb+pl][1], w11, s);
            s = fmaf(s_x[pb+pl][2], w12, s);
            s_hT[c*37 + pb + pl] = fmaxf(s, 0.f);   // same-wave LDS: no barrier
        }
    }
    {
        float acc[8];
        const float bb = b2[c];
        #pragma unroll
        for (int pl = 0; pl < 8; pl++) acc[pl] = bb;
        for (int j = 0; j < 64; j++) {
            const float wv = w2[j*64 + c];
            const float* hr = &s_hT[j*37 + pb];
            #pragma unroll
            for (int pl = 0; pl < 8; pl++) acc[pl] = fmaf(hr[pl], wv, acc[pl]);
        }
        #pragma unroll
        for (int pl = 0; pl < 8; pl++)
            feat[(size_t)(pbase + pb + pl)*64 + c] = fmaxf(acc[pl], 0.f);
    }
}

// ---------------------------------------------------------------------------
// KNN via wave-per-point bitonic top-64 (superset of top-32), branch-free.
__global__ __launch_bounds__(256) void k_knn(
    const float4* __restrict__ c4, int* __restrict__ idx)
{
    __shared__ float4 s_c[N];
    const int tid = threadIdx.x;
    const int w = tid >> 6, lane = tid & 63;
    const int p = blockIdx.x * 4 + w;
    const int b = p >> 11;
    for (int i = tid; i < N; i += 256) s_c[i] = c4[(size_t)b*N + i];
    __syncthreads();
    const float4 me = s_c[p & (N-1)];
    unsigned top = 0x7F800000u;
    for (int t0 = 0; t0 < N; t0 += 64) {
        const float4 s = s_c[t0 + lane];
        float d2 = me.w + s.w - 2.f*(me.x*s.x + me.y*s.y + me.z*s.z);
        d2 = fmaxf(d2, 0.f);
        unsigned v = (__float_as_uint(d2) & 0xFFFFF800u) | (unsigned)(t0 + lane);
        #pragma unroll
        for (int k = 2; k <= 64; k <<= 1) {
            #pragma unroll
            for (int j = k >> 1; j > 0; j >>= 1) {
                const unsigned pv = (unsigned)__shfl_xor((int)v, j, 64);
                const unsigned lo = v < pv ? v : pv;
                const unsigned hi = v < pv ? pv : v;
                v = (((lane & k) == 0) == ((lane & j) == 0)) ? lo : hi;
            }
        }
        const unsigned rb = (unsigned)__shfl((int)v, 63 - lane, 64);
        unsigned mm = top < rb ? top : rb;
        #pragma unroll
        for (int j = 32; j > 0; j >>= 1) {
            const unsigned pv = (unsigned)__shfl_xor((int)mm, j, 64);
            const unsigned lo = mm < pv ? mm : pv;
            const unsigned hi = mm < pv ? pv : mm;
            mm = ((lane & j) == 0) ? lo : hi;
        }
        top = mm;
    }
    if (lane < 32) idx[(size_t)p*KNBR + lane] = (int)(top & 0x7FFu);
}

// ---------------------------------------------------------------------------
// x1 = lrelu(feat @ W1) : [BN,CIN] -> [BN,64]. 32 points/block, 8/wave.
template<int CIN>
__global__ __launch_bounds__(256) void k_unary1(
    const float* __restrict__ feat, const float* __restrict__ w1,
    float* __restrict__ x1)
{
    __shared__ float s_fT[128*36 + 8];
    const int tid = threadIdx.x;
    const int pbase = blockIdx.x * 32;
    for (int i = tid; i < 32*CIN; i += 256) {
        const int p = i / CIN, j = i % CIN;
        s_fT[j*36 + p] = feat[(size_t)pbase*CIN + i];
    }
    __syncthreads();
    const int w = tid >> 6, c = tid & 63;
    const int pb = w * 8;
    float acc[8] = {0.f,0.f,0.f,0.f,0.f,0.f,0.f,0.f};
    for (int j = 0; j < CIN; j++) {
        const float wv = w1[j*64 + c];
        const float* fr = &s_fT[j*36 + pb];
        #pragma unroll
        for (int pl = 0; pl < 8; pl++) acc[pl] = fmaf(fr[pl], wv, acc[pl]);
    }
    #pragma unroll
    for (int pl = 0; pl < 8; pl++)
        x1[(size_t)(pbase + pb + pl)*64 + c] = lrelu(acc[pl]);
}

// ---------------------------------------------------------------------------
// KPConv, LDS-unioned (53.2 KB -> 3 blocks/CU):
//   region AGG  [0,8640)      : transposed agg, pad 9
//   region A    [8640,12480)  : s_w (ph0-1) -> s_part[2048] + s_feat (ph2-3)
//   region X2   [12480,12992)
template<int CIN>
__global__ __launch_bounds__(256) void k_kpconv(
    const float* __restrict__ x1, const float4* __restrict__ c4,
    const float* __restrict__ kp,
    const int* __restrict__ idx, const float* __restrict__ feat_in,
    const float* __restrict__ Wk, const float* __restrict__ W2, const float* __restrict__ Ws,
    float* __restrict__ out)
{
    __shared__ float smem[12992];
    __shared__ int   s_idx[256];
    __shared__ float skp[48];
    float* s_aggT = smem;                 // [960*9]
    float* s_w    = smem + 8640;          // [8*480], dead after phase 1
    float* s_part = smem + 8640;          // [4*512], aliases s_w
    float* s_feat = smem + 8640 + 2048;   // [8*CIN] <= 1024
    float* s_x2   = smem + 12480;         // [512]

    const int tid   = threadIdx.x;
    const int pbase = blockIdx.x * 8;
    const int brow  = pbase & ~(N-1);

    if (tid < NKP*3) skp[tid] = kp[tid];
    s_idx[tid] = idx[(size_t)pbase*KNBR + tid];
    __syncthreads();

    // phase 0: kp influence weights (tid -> pl=tid>>5, k=tid&31)
    {
        const int pl = tid >> 5, k = tid & 31;
        const float4 cp = c4[pbase + pl];
        const float4 cn = c4[brow + s_idx[pl*KNBR + k]];
        const float dx = cn.x - cp.x, dy = cn.y - cp.y, dz = cn.z - cp.z;
        #pragma unroll
        for (int K = 0; K < NKP; K++) {
            const float ex = dx - skp[K*3+0], ey = dy - skp[K*3+1], ez = dz - skp[K*3+2];
            const float dist = sqrtf(ex*ex + ey*ey + ez*ez);
            s_w[pl*480 + K*32 + k] = fmaxf(0.f, 1.f - dist*2.f);
        }
    }
    __syncthreads();

    const int w = tid >> 6, lane = tid & 63;
    // phase 1: neighbor aggregation (wave w -> points 2w,2w+1; lane = channel)
    #pragma unroll
    for (int sub = 0; sub < 2; sub++) {
        const int pl = w*2 + sub;
        float ag[NKP];
        #pragma unroll
        for (int K = 0; K < NKP; K++) ag[K] = 0.f;
        const float* wp = &s_w[pl*480];
        for (int k = 0; k < KNBR; k++) {
            const float val = x1[(size_t)(brow + s_idx[pl*KNBR + k])*64 + lane];
            #pragma unroll
            for (int K = 0; K < NKP; K++) ag[K] = fmaf(wp[K*32 + k], val, ag[K]);
        }
        #pragma unroll
        for (int K = 0; K < NKP; K++) s_aggT[(K*64 + lane)*9 + pl] = ag[K];
    }
    __syncthreads();   // s_w dead from here; region A reused

    // s_feat prefetch (overlaps phase 2 compute)
    for (int i = tid; i < 8*CIN; i += 256) s_feat[i] = feat_in[(size_t)pbase*CIN + i];

    // phase 2: x2 = lrelu(agg @ Wk), split-K: wave w -> j in [240w, 240w+240)
    {
        float acc[8] = {0.f,0.f,0.f,0.f,0.f,0.f,0.f,0.f};
        const int jlo = w * 240, jhi = jlo + 240;
        #pragma unroll 4
        for (int j = jlo; j < jhi; j++) {
            const float wv = Wk[(size_t)j*64 + lane];
            const float* ar = &s_aggT[j*9];
            #pragma unroll
            for (int pl = 0; pl < 8; pl++) acc[pl] = fmaf(ar[pl], wv, acc[pl]);
        }
        #pragma unroll
        for (int pl = 0; pl < 8; pl++) s_part[w*512 + pl*64 + lane] = acc[pl];
    }
    __syncthreads();
    for (int i = tid; i < 512; i += 256)
        s_x2[i] = lrelu(s_part[i] + s_part[512+i] + s_part[1024+i] + s_part[1536+i]);
    __syncthreads();

    // phase 3: out = lrelu(x2@W2 + feat@Ws), register-blocked over 4 points:
    // each W2/Ws load feeds 4 FMAs. wave w -> o in [32w,32w+32); h splits points.
    {
        const int o = (w << 5) + (lane & 31);
        const int h = lane >> 5;
        float acc[4] = {0.f,0.f,0.f,0.f};
        for (int cc = 0; cc < 64; cc++) {
            const float wv = W2[cc*128 + o];
            #pragma unroll
            for (int pi = 0; pi < 4; pi++)
                acc[pi] = fmaf(s_x2[(h*4+pi)*64 + cc], wv, acc[pi]);
        }
        for (int j = 0; j < CIN; j++) {
            const float wv = Ws[j*128 + o];
            #pragma unroll
            for (int pi = 0; pi < 4; pi++)
                acc[pi] = fmaf(s_feat[(h*4+pi)*CIN + j], wv, acc[pi]);
        }
        #pragma unroll
        for (int pi = 0; pi < 4; pi++)
            out[(size_t)(pbase + h*4 + pi)*128 + o] = lrelu(acc[pi]);
    }
}

// ---------------------------------------------------------------------------
// VLAD assignment: a = softmax(f @ wa) * valid; also accumulates sum_a[b,kc].
__global__ __launch_bounds__(256) void k_vlad_a(
    const float* __restrict__ f, const float* __restrict__ wa,
    const int* __restrict__ m, float* __restrict__ a, float* __restrict__ sumA)
{
    __shared__ float s_fT[128*36 + 8];
    __shared__ float s_m[32];
    const int tid = threadIdx.x;
    const int pbase = blockIdx.x * 32;
    const int b = pbase >> 11;
    for (int i = tid; i < 32*128; i += 256) {
        const int p = i >> 7, j = i & 127;
        s_fT[j*36 + p] = f[(size_t)pbase*128 + i];
    }
    if (tid < 32) s_m[tid] = (m[pbase + tid] != 0) ? 0.f : 1.f;
    __syncthreads();
    const int w = tid >> 6, kc = tid & 63;
    const int pb = w * 8;
    float acc[8] = {0.f,0.f,0.f,0.f,0.f,0.f,0.f,0.f};
    for (int j = 0; j < 128; j++) {
        const float wv = wa[j*64 + kc];
        const float* fr = &s_fT[j*36 + pb];
        #pragma unroll
        for (int pl = 0; pl < 8; pl++) acc[pl] = fmaf(fr[pl], wv, acc[pl]);
    }
    float part = 0.f;
    #pragma unroll
    for (int pl = 0; pl < 8; pl++) {
        float mx = acc[pl];
        #pragma unroll
        for (int off = 32; off > 0; off >>= 1) mx = fmaxf(mx, __shfl_xor(mx, off, 64));
        const float e = expf(acc[pl] - mx);
        float se = e;
        #pragma unroll
        for (int off = 32; off > 0; off >>= 1) se += __shfl_xor(se, off, 64);
        const float av = (e / se) * s_m[pb + pl];
        a[(size_t)(pbase + pb + pl)*64 + kc] = av;
        part += av;
    }
    atomicAdd(&sumA[b*64 + kc], part);
}

// ---------------------------------------------------------------------------
// VLAD accumulation: vpart[ch][b][kc][d] = sum_{n in chunk} a[b,n,kc]*f[b,n,d]
// grid = B*VCH blocks, 256 threads, 8x4 register tile per thread.
__global__ __launch_bounds__(256) void k_vlad_acc(
    const float* __restrict__ a, const float* __restrict__ f,
    float* __restrict__ vpart)
{
    __shared__ float s_a[32*64];
    __shared__ float s_f[32*128];
    const int b  = blockIdx.x >> 4;          // VCH = 16
    const int ch = blockIdx.x & 15;
    const int n0 = ch * (N / VCH);           // 128 points per chunk
    const int tid = threadIdx.x;
    const int kc0 = (tid >> 5) * 8;
    const int d0  = (tid & 31) * 4;
    float acc[8][4];
    #pragma unroll
    for (int i = 0; i < 8; i++)
        #pragma unroll
        for (int j = 0; j < 4; j++) acc[i][j] = 0.f;
    for (int t = 0; t < N/VCH; t += 32) {
        __syncthreads();
        const size_t base = (size_t)(b*N + n0 + t);
        for (int i = tid; i < 32*64; i += 256)  s_a[i] = a[(base << 6) + i];
        for (int i = tid; i < 32*128; i += 256) s_f[i] = f[(base << 7) + i];
        __syncthreads();
        for (int n = 0; n < 32; n++) {
            float av[8], fv[4];
            #pragma unroll
            for (int i = 0; i < 8; i++) av[i] = s_a[n*64 + kc0 + i];
            #pragma unroll
            for (int j = 0; j < 4; j++) fv[j] = s_f[n*128 + d0 + j];
            #pragma unroll
            for (int i = 0; i < 8; i++)
                #pragma unroll
                for (int j = 0; j < 4; j++) acc[i][j] = fmaf(av[i], fv[j], acc[i][j]);
        }
    }
    float* vp = vpart + ((size_t)ch*B + b)*8192;
    #pragma unroll
    for (int i = 0; i < 8; i++)
        #pragma unroll
        for (int j = 0; j < 4; j++) vp[(kc0+i)*128 + d0 + j] = acc[i][j];
}

// ---------------------------------------------------------------------------
// Reduce partials, subtract suma*centers, intra-normalize.
__global__ __launch_bounds__(128) void k_vlad_norm(
    const float* __restrict__ vpart, const float* __restrict__ sumA,
    const float* __restrict__ centers, float* __restrict__ v)
{
    const int b = blockIdx.x >> 6, kc = blockIdx.x & 63, d = threadIdx.x;
    float acc = 0.f;
    #pragma unroll
    for (int c = 0; c < VCH; c++)
        acc += vpart[((size_t)c*B + b)*8192 + kc*128 + d];
    const float vv = acc - sumA[b*64 + kc] * centers[kc*128 + d];
    float s2 = vv*vv;
    #pragma unroll
    for (int off = 32; off > 0; off >>= 1) s2 += __shfl_xor(s2, off, 64);
    __shared__ float red[2];
    if ((d & 63) == 0) red[d >> 6] = s2;
    __syncthreads();
    const float tot = red[0] + red[1];
    v[((size_t)b*64 + kc)*128 + d] = vv / (sqrtf(tot) + 1e-8f);
}

// global-norm scale per batch: scale[b] = 1/(||v_b||+1e-8)
__global__ __launch_bounds__(256) void k_vnorm(
    const float* __restrict__ v, float* __restrict__ scale)
{
    const int b = blockIdx.x;
    float s = 0.f;
    for (int i = threadIdx.x; i < 8192; i += 256) { const float t = v[(size_t)b*8192 + i]; s = fmaf(t, t, s); }
    #pragma unroll
    for (int off = 32; off > 0; off >>= 1) s += __shfl_xor(s, off, 64);
    __shared__ float red[4];
    if ((threadIdx.x & 63) == 0) red[threadIdx.x >> 6] = s;
    __syncthreads();
    if (threadIdx.x == 0) {
        const float tot = red[0] + red[1] + red[2] + red[3];
        scale[b] = 1.f / (sqrtf(tot) + 1e-8f);
    }
}

__global__ __launch_bounds__(256) void k_zero(float* __restrict__ p, int n)
{
    const int i = blockIdx.x * 256 + threadIdx.x;
    if (i < n) p[i] = 0.f;
}

// projection: 32 j-chunk blocks, loop all batches; proj fetched exactly once.
__global__ __launch_bounds__(256) void k_proj(
    const float* __restrict__ v, const float* __restrict__ scale,
    const float* __restrict__ proj, float* __restrict__ outacc)
{
    __shared__ float s_v[8*256];
    __shared__ float s_sc[8];
    const int jc = blockIdx.x, o = threadIdx.x;
    const int j0 = jc * 256;
    for (int i = o; i < 8*256; i += 256) {
        const int bb = i >> 8, jj = i & 255;
        s_v[i] = v[(size_t)bb*8192 + j0 + jj];
    }
    if (o < 8) s_sc[o] = scale[o];
    __syncthreads();
    float acc[8] = {0.f,0.f,0.f,0.f,0.f,0.f,0.f,0.f};
    for (int jj = 0; jj < 256; jj++) {
        const float pv = proj[(size_t)(j0+jj)*256 + o];
        #pragma unroll
        for (int bb = 0; bb < 8; bb++) acc[bb] = fmaf(s_v[bb*256 + jj], pv, acc[bb]);
    }
    #pragma unroll
    for (int bb = 0; bb < 8; bb++) atomicAdd(&outacc[bb*256 + o], acc[bb] * s_sc[bb]);
}

// final L2 normalize + f32 store
__global__ __launch_bounds__(256) void k_outnorm(
    const float* __restrict__ outacc, float* __restrict__ out)
{
    const int b = blockIdx.x, o = threadIdx.x;
    const float val = outacc[b*256 + o];
    float s = val*val;
    #pragma unroll
    for (int off = 32; off > 0; off >>= 1) s += __shfl_xor(s, off, 64);
    __shared__ float red[4];
    if ((o & 63) == 0) red[o >> 6] = s;
    __syncthreads();
    const float tot = red[0] + red[1] + red[2] + red[3];
    out[b*256 + o] = val / (sqrtf(tot) + 1e-12f);
}

// ---------------------------------------------------------------------------
extern "C" void kernel_launch(void* const* d_in, const int* in_sizes, int n_in,
                              void* d_out, int out_size, void* d_ws, size_t ws_size,
                              hipStream_t stream)
{
    (void)in_sizes; (void)n_in; (void)out_size; (void)ws_size;
    const float* x     = (const float*)d_in[0];
    const int*   m     = (const int*)  d_in[1];
    const float* pn_w1 = (const float*)d_in[2];
    const float* pn_b1 = (const float*)d_in[3];
    const float* pn_w2 = (const float*)d_in[4];
    const float* pn_b2 = (const float*)d_in[5];
    const float* kp    = (const float*)d_in[6];
    const float* bw1[3] = {(const float*)d_in[7],  (const float*)d_in[11], (const float*)d_in[15]};
    const float* bwk[3] = {(const float*)d_in[8],  (const float*)d_in[12], (const float*)d_in[16]};
    const float* bw2[3] = {(const float*)d_in[9],  (const float*)d_in[13], (const float*)d_in[17]};
    const float* bws[3] = {(const float*)d_in[10], (const float*)d_in[14], (const float*)d_in[18]};
    const float* vlad_wa      = (const float*)d_in[19];
    const float* vlad_centers = (const float*)d_in[20];
    const float* vlad_proj    = (const float*)d_in[21];
    float* out = (float*)d_out;

    char* ws = (char*)d_ws;
    size_t off = 0;
    auto alloc = [&](size_t bytes) -> void* {
        void* p = ws + off;
        off = (off + bytes + 255) & ~(size_t)255;
        return p;
    };
    float4* coords4 = (float4*)alloc((size_t)BN*16);      //  0.26 MB
    float*  feat0   = (float*)alloc((size_t)BN*64*4);     //  4.19 MB
    int*    idxb    = (int*)  alloc((size_t)BN*KNBR*4);   //  2.10 MB
    float*  x1b     = (float*)alloc((size_t)BN*64*4);     //  4.19 MB (aliased by vpart)
    float*  fA      = (float*)alloc((size_t)BN*128*4);    //  8.39 MB
    float*  fB      = (float*)alloc((size_t)BN*128*4);    //  8.39 MB
    float*  abuf    = (float*)alloc((size_t)BN*64*4);     //  4.19 MB
    float*  vbuf    = (float*)alloc((size_t)B*8192*4);    //  0.26 MB
    float*  scaleb  = (float*)alloc((size_t)B*4);
    float*  sumA    = (float*)alloc((size_t)B*64*4);      // contiguous with outacc
    float*  outacc  = (float*)alloc((size_t)B*256*4);
    float*  vpart   = x1b;  // VCH*B*8192*4 = 4.19 MB; x1b dead after last kpconv

    k_zero<<<(B*64 + B*256 + 255)/256, 256, 0, stream>>>(sumA, B*64 + B*256);
    k_pointnet<<<BN/32, 256, 0, stream>>>(x, m, pn_w1, pn_b1, pn_w2, pn_b2, feat0, coords4);
    k_knn<<<BN/4, 256, 0, stream>>>(coords4, idxb);

    k_unary1<64> <<<BN/32, 256, 0, stream>>>(feat0, bw1[0], x1b);
    k_kpconv<64> <<<BN/8, 256, 0, stream>>>(x1b, coords4, kp, idxb, feat0, bwk[0], bw2[0], bws[0], fA);
    k_unary1<128><<<BN/32, 256, 0, stream>>>(fA, bw1[1], x1b);
    k_kpconv<128><<<BN/8, 256, 0, stream>>>(x1b, coords4, kp, idxb, fA, bwk[1], bw2[1], bws[1], fB);
    k_unary1<128><<<BN/32, 256, 0, stream>>>(fB, bw1[2], x1b);
    k_kpconv<128><<<BN/8, 256, 0, stream>>>(x1b, coords4, kp, idxb, fB, bwk[2], bw2[2], bws[2], fA);

    k_vlad_a<<<BN/32, 256, 0, stream>>>(fA, vlad_wa, m, abuf, sumA);
    k_vlad_acc<<<B*VCH, 256, 0, stream>>>(abuf, fA, vpart);
    k_vlad_norm<<<B*64, 128, 0, stream>>>(vpart, sumA, vlad_centers, vbuf);
    k_vnorm<<<B, 256, 0, stream>>>(vbuf, scaleb);
    k_proj<<<32, 256, 0, stream>>>(vbuf, scaleb, vlad_proj, outacc);
    k_outnorm<<<B, 256, 0, stream>>>(outacc, out);
}

// Round 6
// 675.861 us; speedup vs baseline: 1.9992x; 1.0371x over previous
//
#include <hip/hip_runtime.h>
#include <hip/hip_bf16.h>

#define B 8
#define N 2048
#define BN (B*N)
#define KNBR 32
#define NKP 15
#define VCH 16   // n-chunks per batch in VLAD accumulation

__device__ __forceinline__ float lrelu(float x){ return x > 0.f ? x : 0.1f*x; }
__device__ __forceinline__ unsigned umin_(unsigned a, unsigned b){ return a < b ? a : b; }
__device__ __forceinline__ unsigned umax_(unsigned a, unsigned b){ return a < b ? b : a; }

// ---------------------------------------------------------------------------
// PointNet: f = relu(relu(x@W1+b1)@W2+b2); emits coords4 = (masked xyz, sq).
// block = 256 threads = 32 points; each wave handles 8 points (weight-reuse).
__global__ __launch_bounds__(256) void k_pointnet(
    const float* __restrict__ x, const int* __restrict__ m,
    const float* __restrict__ w1, const float* __restrict__ b1,
    const float* __restrict__ w2, const float* __restrict__ b2,
    float* __restrict__ feat, float4* __restrict__ coords4)
{
    __shared__ float s_x[32][3];
    __shared__ __align__(16) float s_hT[64*40];   // transposed hidden, stride 40 (16B-aligned rows)
    const int tid = threadIdx.x;
    const int pbase = blockIdx.x * 32;
    if (tid < 32) {
        const int p = pbase + tid;
        const float x0 = x[p*3+0], x1v = x[p*3+1], x2v = x[p*3+2];
        s_x[tid][0] = x0; s_x[tid][1] = x1v; s_x[tid][2] = x2v;
        const bool mm = (m[p] != 0);
        const float cx = mm ? 1e6f : x0, cy = mm ? 1e6f : x1v, cz = mm ? 1e6f : x2v;
        coords4[p] = make_float4(cx, cy, cz, cx*cx + cy*cy + cz*cz);
    }
    __syncthreads();
    const int w = tid >> 6, c = tid & 63;
    const int pb = w * 8;
    {
        const float w10 = w1[c], w11 = w1[64+c], w12 = w1[128+c], bb = b1[c];
        #pragma unroll
        for (int pl = 0; pl < 8; pl++) {
            float s = bb;
            s = fmaf(s_x[pb+pl][0], w10, s);
            s = fmaf(s_x[pb+pl][1], w11, s);
            s = fmaf(s_x[pb+pl][2], w12, s);
            s_hT[c*40 + pb + pl] = fmaxf(s, 0.f);   // same-wave LDS: no barrier
        }
    }
    {
        float acc[8];
        const float bb = b2[c];
        #pragma unroll
        for (int pl = 0; pl < 8; pl++) acc[pl] = bb;
        for (int j = 0; j < 64; j++) {
            const float wv = w2[j*64 + c];
            const float4 h0 = *(const float4*)&s_hT[j*40 + pb];
            const float4 h1 = *(const float4*)&s_hT[j*40 + pb + 4];
            acc[0] = fmaf(h0.x, wv, acc[0]); acc[1] = fmaf(h0.y, wv, acc[1]);
            acc[2] = fmaf(h0.z, wv, acc[2]); acc[3] = fmaf(h0.w, wv, acc[3]);
            acc[4] = fmaf(h1.x, wv, acc[4]); acc[5] = fmaf(h1.y, wv, acc[5]);
            acc[6] = fmaf(h1.z, wv, acc[6]); acc[7] = fmaf(h1.w, wv, acc[7]);
        }
        #pragma unroll
        for (int pl = 0; pl < 8; pl++)
            feat[(size_t)(pbase + pb + pl)*64 + c] = fmaxf(acc[pl], 0.f);
    }
}

// ---------------------------------------------------------------------------
// KNN: wave handles TWO points (independent sort chains -> 2x ILP to hide
// bpermute latency). Bitonic top-64 (superset of top-32), branch-free.
// block = 256 = 4 waves = 8 points.
__global__ __launch_bounds__(256) void k_knn(
    const float4* __restrict__ c4, int* __restrict__ idx)
{
    __shared__ float4 s_c[N];
    const int tid = threadIdx.x;
    const int w = tid >> 6, lane = tid & 63;
    const int p0 = blockIdx.x * 8 + w*2;
    const int b = p0 >> 11;
    for (int i = tid; i < N; i += 256) s_c[i] = c4[(size_t)b*N + i];
    __syncthreads();
    const float4 meA = s_c[p0 & (N-1)];
    const float4 meB = s_c[(p0+1) & (N-1)];
    unsigned topA = 0x7F800000u, topB = 0x7F800000u;
    for (int t0 = 0; t0 < N; t0 += 64) {
        const float4 s = s_c[t0 + lane];
        float dA = meA.w + s.w - 2.f*(meA.x*s.x + meA.y*s.y + meA.z*s.z);
        float dB = meB.w + s.w - 2.f*(meB.x*s.x + meB.y*s.y + meB.z*s.z);
        dA = fmaxf(dA, 0.f); dB = fmaxf(dB, 0.f);
        unsigned vA = (__float_as_uint(dA) & 0xFFFFF800u) | (unsigned)(t0 + lane);
        unsigned vB = (__float_as_uint(dB) & 0xFFFFF800u) | (unsigned)(t0 + lane);
        #pragma unroll
        for (int k = 2; k <= 64; k <<= 1) {
            #pragma unroll
            for (int j = k >> 1; j > 0; j >>= 1) {
                const bool up = (((lane & k) == 0) == ((lane & j) == 0));
                const unsigned pA = (unsigned)__shfl_xor((int)vA, j, 64);
                const unsigned pB = (unsigned)__shfl_xor((int)vB, j, 64);
                vA = up ? umin_(vA,pA) : umax_(vA,pA);
                vB = up ? umin_(vB,pB) : umax_(vB,pB);
            }
        }
        const unsigned rA = (unsigned)__shfl((int)vA, 63 - lane, 64);
        const unsigned rB = (unsigned)__shfl((int)vB, 63 - lane, 64);
        unsigned mA = umin_(topA, rA), mB = umin_(topB, rB);
        #pragma unroll
        for (int j = 32; j > 0; j >>= 1) {
            const bool up = ((lane & j) == 0);
            const unsigned pA = (unsigned)__shfl_xor((int)mA, j, 64);
            const unsigned pB = (unsigned)__shfl_xor((int)mB, j, 64);
            mA = up ? umin_(mA,pA) : umax_(mA,pA);
            mB = up ? umin_(mB,pB) : umax_(mB,pB);
        }
        topA = mA; topB = mB;
    }
    if (lane < 32) {
        idx[(size_t)p0*KNBR + lane]     = (int)(topA & 0x7FFu);
        idx[(size_t)(p0+1)*KNBR + lane] = (int)(topB & 0x7FFu);
    }
}

// ---------------------------------------------------------------------------
// x1 = lrelu(feat @ W1) : [BN,CIN] -> [BN,64]. 32 points/block, 8/wave.
// s_fT rows stride 36 -> (36j+8w)*4 is 16B-aligned: float4 broadcast reads.
template<int CIN>
__global__ __launch_bounds__(256) void k_unary1(
    const float* __restrict__ feat, const float* __restrict__ w1,
    float* __restrict__ x1)
{
    __shared__ __align__(16) float s_fT[128*36 + 8];
    const int tid = threadIdx.x;
    const int pbase = blockIdx.x * 32;
    for (int i = tid; i < 32*CIN; i += 256) {
        const int p = i / CIN, j = i % CIN;
        s_fT[j*36 + p] = feat[(size_t)pbase*CIN + i];
    }
    __syncthreads();
    const int w = tid >> 6, c = tid & 63;
    const int pb = w * 8;
    float acc[8] = {0.f,0.f,0.f,0.f,0.f,0.f,0.f,0.f};
    for (int j = 0; j < CIN; j++) {
        const float wv = w1[j*64 + c];
        const float4 f0 = *(const float4*)&s_fT[j*36 + pb];
        const float4 f1 = *(const float4*)&s_fT[j*36 + pb + 4];
        acc[0] = fmaf(f0.x, wv, acc[0]); acc[1] = fmaf(f0.y, wv, acc[1]);
        acc[2] = fmaf(f0.z, wv, acc[2]); acc[3] = fmaf(f0.w, wv, acc[3]);
        acc[4] = fmaf(f1.x, wv, acc[4]); acc[5] = fmaf(f1.y, wv, acc[5]);
        acc[6] = fmaf(f1.z, wv, acc[6]); acc[7] = fmaf(f1.w, wv, acc[7]);
    }
    #pragma unroll
    for (int pl = 0; pl < 8; pl++)
        x1[(size_t)(pbase + pb + pl)*64 + c] = lrelu(acc[pl]);
}

// ---------------------------------------------------------------------------
// KPConv, LDS-unioned (~49.3 KB -> 3 blocks/CU), b128 broadcast reads:
//   s_aggT  [0,7680)        : transposed agg, stride 8 (16B rows)
//   region A[7680,11520)    : s_w (ph0-1) -> s_part[2048]+s_featT[8*CIN] (ph2-3)
//   s_x2T   [11520,12032)   : x2 transposed, stride 8
template<int CIN>
__global__ __launch_bounds__(256) void k_kpconv(
    const float* __restrict__ x1, const float4* __restrict__ c4,
    const float* __restrict__ kp,
    const int* __restrict__ idx, const float* __restrict__ feat_in,
    const float* __restrict__ Wk, const float* __restrict__ W2, const float* __restrict__ Ws,
    float* __restrict__ out)
{
    __shared__ __align__(16) float smem[12032];
    __shared__ int   s_idx[256];
    __shared__ float skp[48];
    float* s_aggT = smem;                 // [960*8]
    float* s_w    = smem + 7680;          // [8*480], dead after phase 1
    float* s_part = smem + 7680;          // [4*512], aliases s_w
    float* s_featT= smem + 7680 + 2048;   // [CIN*8] <= 1024, transposed stride 8
    float* s_x2T  = smem + 11520;         // [64*8], transposed stride 8

    const int tid   = threadIdx.x;
    const int pbase = blockIdx.x * 8;
    const int brow  = pbase & ~(N-1);

    if (tid < NKP*3) skp[tid] = kp[tid];
    s_idx[tid] = idx[(size_t)pbase*KNBR + tid];
    __syncthreads();

    // phase 0: kp influence weights (tid -> pl=tid>>5, k=tid&31)
    {
        const int pl = tid >> 5, k = tid & 31;
        const float4 cp = c4[pbase + pl];
        const float4 cn = c4[brow + s_idx[pl*KNBR + k]];
        const float dx = cn.x - cp.x, dy = cn.y - cp.y, dz = cn.z - cp.z;
        #pragma unroll
        for (int K = 0; K < NKP; K++) {
            const float ex = dx - skp[K*3+0], ey = dy - skp[K*3+1], ez = dz - skp[K*3+2];
            const float dist = sqrtf(ex*ex + ey*ey + ez*ez);
            s_w[pl*480 + K*32 + k] = fmaxf(0.f, 1.f - dist*2.f);
        }
    }
    __syncthreads();

    const int w = tid >> 6, lane = tid & 63;
    // phase 1: neighbor aggregation (wave w -> points 2w,2w+1; lane = channel)
    #pragma unroll
    for (int sub = 0; sub < 2; sub++) {
        const int pl = w*2 + sub;
        float ag[NKP];
        #pragma unroll
        for (int K = 0; K < NKP; K++) ag[K] = 0.f;
        const float* wp = &s_w[pl*480];
        for (int k = 0; k < KNBR; k++) {
            const float val = x1[(size_t)(brow + s_idx[pl*KNBR + k])*64 + lane];
            #pragma unroll
            for (int K = 0; K < NKP; K++) ag[K] = fmaf(wp[K*32 + k], val, ag[K]);
        }
        #pragma unroll
        for (int K = 0; K < NKP; K++) s_aggT[(K*64 + lane)*8 + pl] = ag[K];
    }
    __syncthreads();   // s_w dead from here; region A reused

    // s_featT prefetch (transposed, stride 8), overlaps phase 2 compute
    for (int i = tid; i < 8*CIN; i += 256) {
        const int p = i / CIN, j = i % CIN;       // global read coalesced over i
        s_featT[j*8 + p] = feat_in[(size_t)pbase*CIN + i];
    }

    // phase 2: x2 = lrelu(agg @ Wk), split-K: wave w -> j in [240w, 240w+240)
    {
        float acc[8] = {0.f,0.f,0.f,0.f,0.f,0.f,0.f,0.f};
        const int jlo = w * 240, jhi = jlo + 240;
        #pragma unroll 4
        for (int j = jlo; j < jhi; j++) {
            const float wv = Wk[(size_t)j*64 + lane];
            const float4 a0 = *(const float4*)&s_aggT[j*8];
            const float4 a1 = *(const float4*)&s_aggT[j*8 + 4];
            acc[0] = fmaf(a0.x, wv, acc[0]); acc[1] = fmaf(a0.y, wv, acc[1]);
            acc[2] = fmaf(a0.z, wv, acc[2]); acc[3] = fmaf(a0.w, wv, acc[3]);
            acc[4] = fmaf(a1.x, wv, acc[4]); acc[5] = fmaf(a1.y, wv, acc[5]);
            acc[6] = fmaf(a1.z, wv, acc[6]); acc[7] = fmaf(a1.w, wv, acc[7]);
        }
        #pragma unroll
        for (int pl = 0; pl < 8; pl++) s_part[w*512 + pl*64 + lane] = acc[pl];
    }
    __syncthreads();
    for (int i = tid; i < 512; i += 256) {
        const int pl = i >> 6, c = i & 63;
        s_x2T[c*8 + pl] = lrelu(s_part[i] + s_part[512+i] + s_part[1024+i] + s_part[1536+i]);
    }
    __syncthreads();

    // phase 3: out = lrelu(x2@W2 + feat@Ws); wave w -> o in [32w,32w+32),
    // h = lane>>5 splits points; each weight load feeds 4 FMAs via b128 reads.
    {
        const int o = (w << 5) + (lane & 31);
        const int h = lane >> 5;
        float acc[4] = {0.f,0.f,0.f,0.f};
        for (int cc = 0; cc < 64; cc++) {
            const float wv = W2[cc*128 + o];
            const float4 xv = *(const float4*)&s_x2T[cc*8 + h*4];
            acc[0] = fmaf(xv.x, wv, acc[0]); acc[1] = fmaf(xv.y, wv, acc[1]);
            acc[2] = fmaf(xv.z, wv, acc[2]); acc[3] = fmaf(xv.w, wv, acc[3]);
        }
        for (int j = 0; j < CIN; j++) {
            const float wv = Ws[j*128 + o];
            const float4 fv = *(const float4*)&s_featT[j*8 + h*4];
            acc[0] = fmaf(fv.x, wv, acc[0]); acc[1] = fmaf(fv.y, wv, acc[1]);
            acc[2] = fmaf(fv.z, wv, acc[2]); acc[3] = fmaf(fv.w, wv, acc[3]);
        }
        #pragma unroll
        for (int pi = 0; pi < 4; pi++)
            out[(size_t)(pbase + h*4 + pi)*128 + o] = lrelu(acc[pi]);
    }
}

// ---------------------------------------------------------------------------
// VLAD assignment: a = softmax(f @ wa) * valid; also accumulates sum_a[b,kc].
__global__ __launch_bounds__(256) void k_vlad_a(
    const float* __restrict__ f, const float* __restrict__ wa,
    const int* __restrict__ m, float* __restrict__ a, float* __restrict__ sumA)
{
    __shared__ __align__(16) float s_fT[128*36 + 8];
    __shared__ float s_m[32];
    const int tid = threadIdx.x;
    const int pbase = blockIdx.x * 32;
    const int b = pbase >> 11;
    for (int i = tid; i < 32*128; i += 256) {
        const int p = i >> 7, j = i & 127;
        s_fT[j*36 + p] = f[(size_t)pbase*128 + i];
    }
    if (tid < 32) s_m[tid] = (m[pbase + tid] != 0) ? 0.f : 1.f;
    __syncthreads();
    const int w = tid >> 6, kc = tid & 63;
    const int pb = w * 8;
    float acc[8] = {0.f,0.f,0.f,0.f,0.f,0.f,0.f,0.f};
    for (int j = 0; j < 128; j++) {
        const float wv = wa[j*64 + kc];
        const float4 f0 = *(const float4*)&s_fT[j*36 + pb];
        const float4 f1 = *(const float4*)&s_fT[j*36 + pb + 4];
        acc[0] = fmaf(f0.x, wv, acc[0]); acc[1] = fmaf(f0.y, wv, acc[1]);
        acc[2] = fmaf(f0.z, wv, acc[2]); acc[3] = fmaf(f0.w, wv, acc[3]);
        acc[4] = fmaf(f1.x, wv, acc[4]); acc[5] = fmaf(f1.y, wv, acc[5]);
        acc[6] = fmaf(f1.z, wv, acc[6]); acc[7] = fmaf(f1.w, wv, acc[7]);
    }
    float part = 0.f;
    #pragma unroll
    for (int pl = 0; pl < 8; pl++) {
        float mx = acc[pl];
        #pragma unroll
        for (int off = 32; off > 0; off >>= 1) mx = fmaxf(mx, __shfl_xor(mx, off, 64));
        const float e = expf(acc[pl] - mx);
        float se = e;
        #pragma unroll
        for (int off = 32; off > 0; off >>= 1) se += __shfl_xor(se, off, 64);
        const float av = (e / se) * s_m[pb + pl];
        a[(size_t)(pbase + pb + pl)*64 + kc] = av;
        part += av;
    }
    atomicAdd(&sumA[b*64 + kc], part);
}

// ---------------------------------------------------------------------------
// VLAD accumulation: vpart[ch][b][kc][d] = sum_{n in chunk} a[b,n,kc]*f[b,n,d]
// grid = B*VCH blocks, 256 threads, 8x4 register tile, float4 LDS reads.
__global__ __launch_bounds__(256) void k_vlad_acc(
    const float* __restrict__ a, const float* __restrict__ f,
    float* __restrict__ vpart)
{
    __shared__ __align__(16) float s_a[32*64];
    __shared__ __align__(16) float s_f[32*128];
    const int b  = blockIdx.x >> 4;          // VCH = 16
    const int ch = blockIdx.x & 15;
    const int n0 = ch * (N / VCH);           // 128 points per chunk
    const int tid = threadIdx.x;
    const int kc0 = (tid >> 5) * 8;
    const int d0  = (tid & 31) * 4;
    float acc[8][4];
    #pragma unroll
    for (int i = 0; i < 8; i++)
        #pragma unroll
        for (int j = 0; j < 4; j++) acc[i][j] = 0.f;
    for (int t = 0; t < N/VCH; t += 32) {
        __syncthreads();
        const size_t base = (size_t)(b*N + n0 + t);
        for (int i = tid; i < 32*64; i += 256)  s_a[i] = a[(base << 6) + i];
        for (int i = tid; i < 32*128; i += 256) s_f[i] = f[(base << 7) + i];
        __syncthreads();
        for (int n = 0; n < 32; n++) {
            const float4 a0 = *(const float4*)&s_a[n*64 + kc0];
            const float4 a1 = *(const float4*)&s_a[n*64 + kc0 + 4];
            const float4 fv = *(const float4*)&s_f[n*128 + d0];
            const float av[8] = {a0.x,a0.y,a0.z,a0.w,a1.x,a1.y,a1.z,a1.w};
            const float fw[4] = {fv.x,fv.y,fv.z,fv.w};
            #pragma unroll
            for (int i = 0; i < 8; i++)
                #pragma unroll
                for (int j = 0; j < 4; j++) acc[i][j] = fmaf(av[i], fw[j], acc[i][j]);
        }
    }
    float* vp = vpart + ((size_t)ch*B + b)*8192;
    #pragma unroll
    for (int i = 0; i < 8; i++)
        #pragma unroll
        for (int j = 0; j < 4; j++) vp[(kc0+i)*128 + d0 + j] = acc[i][j];
}

// ---------------------------------------------------------------------------
// Reduce partials, subtract suma*centers, intra-normalize.
__global__ __launch_bounds__(128) void k_vlad_norm(
    const float* __restrict__ vpart, const float* __restrict__ sumA,
    const float* __restrict__ centers, float* __restrict__ v)
{
    const int b = blockIdx.x >> 6, kc = blockIdx.x & 63, d = threadIdx.x;
    float acc = 0.f;
    #pragma unroll
    for (int c = 0; c < VCH; c++)
        acc += vpart[((size_t)c*B + b)*8192 + kc*128 + d];
    const float vv = acc - sumA[b*64 + kc] * centers[kc*128 + d];
    float s2 = vv*vv;
    #pragma unroll
    for (int off = 32; off > 0; off >>= 1) s2 += __shfl_xor(s2, off, 64);
    __shared__ float red[2];
    if ((d & 63) == 0) red[d >> 6] = s2;
    __syncthreads();
    const float tot = red[0] + red[1];
    v[((size_t)b*64 + kc)*128 + d] = vv / (sqrtf(tot) + 1e-8f);
}

// global-norm scale per batch: scale[b] = 1/(||v_b||+1e-8)
__global__ __launch_bounds__(256) void k_vnorm(
    const float* __restrict__ v, float* __restrict__ scale)
{
    const int b = blockIdx.x;
    float s = 0.f;
    for (int i = threadIdx.x; i < 8192; i += 256) { const float t = v[(size_t)b*8192 + i]; s = fmaf(t, t, s); }
    #pragma unroll
    for (int off = 32; off > 0; off >>= 1) s += __shfl_xor(s, off, 64);
    __shared__ float red[4];
    if ((threadIdx.x & 63) == 0) red[threadIdx.x >> 6] = s;
    __syncthreads();
    if (threadIdx.x == 0) {
        const float tot = red[0] + red[1] + red[2] + red[3];
        scale[b] = 1.f / (sqrtf(tot) + 1e-8f);
    }
}

__global__ __launch_bounds__(256) void k_zero(float* __restrict__ p, int n)
{
    const int i = blockIdx.x * 256 + threadIdx.x;
    if (i < n) p[i] = 0.f;
}

// projection: 32 j-chunk blocks, loop all batches; proj fetched exactly once.
__global__ __launch_bounds__(256) void k_proj(
    const float* __restrict__ v, const float* __restrict__ scale,
    const float* __restrict__ proj, float* __restrict__ outacc)
{
    __shared__ __align__(16) float s_v[8*256];
    __shared__ float s_sc[8];
    const int jc = blockIdx.x, o = threadIdx.x;
    const int j0 = jc * 256;
    for (int i = o; i < 8*256; i += 256) {
        const int bb = i >> 8, jj = i & 255;
        s_v[i] = v[(size_t)bb*8192 + j0 + jj];
    }
    if (o < 8) s_sc[o] = scale[o];
    __syncthreads();
    float acc[8] = {0.f,0.f,0.f,0.f,0.f,0.f,0.f,0.f};
    for (int jj = 0; jj < 256; jj += 4) {
        float pv[4];
        #pragma unroll
        for (int q = 0; q < 4; q++) pv[q] = proj[(size_t)(j0+jj+q)*256 + o];
        #pragma unroll
        for (int bb = 0; bb < 8; bb++) {
            const float4 vv = *(const float4*)&s_v[bb*256 + jj];
            acc[bb] = fmaf(vv.x, pv[0], acc[bb]);
            acc[bb] = fmaf(vv.y, pv[1], acc[bb]);
            acc[bb] = fmaf(vv.z, pv[2], acc[bb]);
            acc[bb] = fmaf(vv.w, pv[3], acc[bb]);
        }
    }
    #pragma unroll
    for (int bb = 0; bb < 8; bb++) atomicAdd(&outacc[bb*256 + o], acc[bb] * s_sc[bb]);
}

// final L2 normalize + f32 store
__global__ __launch_bounds__(256) void k_outnorm(
    const float* __restrict__ outacc, float* __restrict__ out)
{
    const int b = blockIdx.x, o = threadIdx.x;
    const float val = outacc[b*256 + o];
    float s = val*val;
    #pragma unroll
    for (int off = 32; off > 0; off >>= 1) s += __shfl_xor(s, off, 64);
    __shared__ float red[4];
    if ((o & 63) == 0) red[o >> 6] = s;
    __syncthreads();
    const float tot = red[0] + red[1] + red[2] + red[3];
    out[b*256 + o] = val / (sqrtf(tot) + 1e-12f);
}

// ---------------------------------------------------------------------------
extern "C" void kernel_launch(void* const* d_in, const int* in_sizes, int n_in,
                              void* d_out, int out_size, void* d_ws, size_t ws_size,
                              hipStream_t stream)
{
    (void)in_sizes; (void)n_in; (void)out_size; (void)ws_size;
    const float* x     = (const float*)d_in[0];
    const int*   m     = (const int*)  d_in[1];
    const float* pn_w1 = (const float*)d_in[2];
    const float* pn_b1 = (const float*)d_in[3];
    const float* pn_w2 = (const float*)d_in[4];
    const float* pn_b2 = (const float*)d_in[5];
    const float* kp    = (const float*)d_in[6];
    const float* bw1[3] = {(const float*)d_in[7],  (const float*)d_in[11], (const float*)d_in[15]};
    const float* bwk[3] = {(const float*)d_in[8],  (const float*)d_in[12], (const float*)d_in[16]};
    const float* bw2[3] = {(const float*)d_in[9],  (const float*)d_in[13], (const float*)d_in[17]};
    const float* bws[3] = {(const float*)d_in[10], (const float*)d_in[14], (const float*)d_in[18]};
    const float* vlad_wa      = (const float*)d_in[19];
    const float* vlad_centers = (const float*)d_in[20];
    const float* vlad_proj    = (const float*)d_in[21];
    float* out = (float*)d_out;

    char* ws = (char*)d_ws;
    size_t off = 0;
    auto alloc = [&](size_t bytes) -> void* {
        void* p = ws + off;
        off = (off + bytes + 255) & ~(size_t)255;
        return p;
    };
    float4* coords4 = (float4*)alloc((size_t)BN*16);      //  0.26 MB
    float*  feat0   = (float*)alloc((size_t)BN*64*4);     //  4.19 MB
    int*    idxb    = (int*)  alloc((size_t)BN*KNBR*4);   //  2.10 MB
    float*  x1b     = (float*)alloc((size_t)BN*64*4);     //  4.19 MB (aliased by vpart)
    float*  fA      = (float*)alloc((size_t)BN*128*4);    //  8.39 MB
    float*  fB      = (float*)alloc((size_t)BN*128*4);    //  8.39 MB
    float*  abuf    = (float*)alloc((size_t)BN*64*4);     //  4.19 MB
    float*  vbuf    = (float*)alloc((size_t)B*8192*4);    //  0.26 MB
    float*  scaleb  = (float*)alloc((size_t)B*4);
    float*  sumA    = (float*)alloc((size_t)B*64*4);      // contiguous with outacc
    float*  outacc  = (float*)alloc((size_t)B*256*4);
    float*  vpart   = x1b;  // VCH*B*8192*4 = 4.19 MB; x1b dead after last kpconv

    k_zero<<<(B*64 + B*256 + 255)/256, 256, 0, stream>>>(sumA, B*64 + B*256);
    k_pointnet<<<BN/32, 256, 0, stream>>>(x, m, pn_w1, pn_b1, pn_w2, pn_b2, feat0, coords4);
    k_knn<<<BN/8, 256, 0, stream>>>(coords4, idxb);

    k_unary1<64> <<<BN/32, 256, 0, stream>>>(feat0, bw1[0], x1b);
    k_kpconv<64> <<<BN/8, 256, 0, stream>>>(x1b, coords4, kp, idxb, feat0, bwk[0], bw2[0], bws[0], fA);
    k_unary1<128><<<BN/32, 256, 0, stream>>>(fA, bw1[1], x1b);
    k_kpconv<128><<<BN/8, 256, 0, stream>>>(x1b, coords4, kp, idxb, fA, bwk[1], bw2[1], bws[1], fB);
    k_unary1<128><<<BN/32, 256, 0, stream>>>(fB, bw1[2], x1b);
    k_kpconv<128><<<BN/8, 256, 0, stream>>>(x1b, coords4, kp, idxb, fB, bwk[2], bw2[2], bws[2], fA);

    k_vlad_a<<<BN/32, 256, 0, stream>>>(fA, vlad_wa, m, abuf, sumA);
    k_vlad_acc<<<B*VCH, 256, 0, stream>>>(abuf, fA, vpart);
    k_vlad_norm<<<B*64, 128, 0, stream>>>(vpart, sumA, vlad_centers, vbuf);
    k_vnorm<<<B, 256, 0, stream>>>(vbuf, scaleb);
    k_proj<<<32, 256, 0, stream>>>(vbuf, scaleb, vlad_proj, outacc);
    k_outnorm<<<B, 256, 0, stream>>>(outacc, out);
}

// Round 7
// 624.223 us; speedup vs baseline: 2.1646x; 1.0827x over previous
//
#include <hip/hip_runtime.h>
#include <hip/hip_bf16.h>

#define B 8
#define N 2048
#define BN (B*N)
#define KNBR 32
#define NKP 15
#define VCH 16   // n-chunks per batch in VLAD accumulation

__device__ __forceinline__ float lrelu(float x){ return x > 0.f ? x : 0.1f*x; }
__device__ __forceinline__ unsigned umin_(unsigned a, unsigned b){ return a < b ? a : b; }
__device__ __forceinline__ unsigned umax_(unsigned a, unsigned b){ return a < b ? b : a; }

// ---------------------------------------------------------------------------
// PointNet: f = relu(relu(x@W1+b1)@W2+b2); emits coords4 = (masked xyz, sq).
// block = 256 threads = 32 points; each wave handles 8 points (weight-reuse).
__global__ __launch_bounds__(256) void k_pointnet(
    const float* __restrict__ x, const int* __restrict__ m,
    const float* __restrict__ w1, const float* __restrict__ b1,
    const float* __restrict__ w2, const float* __restrict__ b2,
    float* __restrict__ feat, float4* __restrict__ coords4)
{
    __shared__ float s_x[32][3];
    __shared__ __align__(16) float s_hT[64*40];   // transposed hidden, stride 40 (16B-aligned rows)
    const int tid = threadIdx.x;
    const int pbase = blockIdx.x * 32;
    if (tid < 32) {
        const int p = pbase + tid;
        const float x0 = x[p*3+0], x1v = x[p*3+1], x2v = x[p*3+2];
        s_x[tid][0] = x0; s_x[tid][1] = x1v; s_x[tid][2] = x2v;
        const bool mm = (m[p] != 0);
        const float cx = mm ? 1e6f : x0, cy = mm ? 1e6f : x1v, cz = mm ? 1e6f : x2v;
        coords4[p] = make_float4(cx, cy, cz, cx*cx + cy*cy + cz*cz);
    }
    __syncthreads();
    const int w = tid >> 6, c = tid & 63;
    const int pb = w * 8;
    {
        const float w10 = w1[c], w11 = w1[64+c], w12 = w1[128+c], bb = b1[c];
        #pragma unroll
        for (int pl = 0; pl < 8; pl++) {
            float s = bb;
            s = fmaf(s_x[pb+pl][0], w10, s);
            s = fmaf(s_x[pb+pl][1], w11, s);
            s = fmaf(s_x[pb+pl][2], w12, s);
            s_hT[c*40 + pb + pl] = fmaxf(s, 0.f);   // same-wave LDS: no barrier
        }
    }
    {
        float acc[8];
        const float bb = b2[c];
        #pragma unroll
        for (int pl = 0; pl < 8; pl++) acc[pl] = bb;
        for (int j = 0; j < 64; j++) {
            const float wv = w2[j*64 + c];
            const float4 h0 = *(const float4*)&s_hT[j*40 + pb];
            const float4 h1 = *(const float4*)&s_hT[j*40 + pb + 4];
            acc[0] = fmaf(h0.x, wv, acc[0]); acc[1] = fmaf(h0.y, wv, acc[1]);
            acc[2] = fmaf(h0.z, wv, acc[2]); acc[3] = fmaf(h0.w, wv, acc[3]);
            acc[4] = fmaf(h1.x, wv, acc[4]); acc[5] = fmaf(h1.y, wv, acc[5]);
            acc[6] = fmaf(h1.z, wv, acc[6]); acc[7] = fmaf(h1.w, wv, acc[7]);
        }
        #pragma unroll
        for (int pl = 0; pl < 8; pl++)
            feat[(size_t)(pbase + pb + pl)*64 + c] = fmaxf(acc[pl], 0.f);
    }
}

// ---------------------------------------------------------------------------
// KNN: one point per wave. Each lane sorts 32 strided candidates ascending
// IN REGISTERS (bitonic network, zero cross-lane ops), then 6 hypercube
// rounds: keep-lowest-32 vs partner (32 shfls) + in-register bitonic
// re-merge (zero shfls). Cross-lane ops/point: 192 vs 896 in the old scheme.
// Packing identical to before: (d2 & ~0x7FF) | idx -> same top-32 set.
__global__ __launch_bounds__(256) void k_knn(
    const float4* __restrict__ c4, int* __restrict__ idx)
{
    __shared__ float4 s_c[N];
    const int tid = threadIdx.x;
    const int w = tid >> 6, lane = tid & 63;
    const int p = blockIdx.x * 4 + w;
    const int b = p >> 11;
    for (int i = tid; i < N; i += 256) s_c[i] = c4[(size_t)b*N + i];
    __syncthreads();
    const float4 me = s_c[p & (N-1)];

    unsigned A[32];
    #pragma unroll
    for (int j = 0; j < 32; j++) {
        const float4 s = s_c[j*64 + lane];
        float d2 = me.w + s.w - 2.f*(me.x*s.x + me.y*s.y + me.z*s.z);
        d2 = fmaxf(d2, 0.f);
        A[j] = (__float_as_uint(d2) & 0xFFFFF800u) | (unsigned)(j*64 + lane);
    }

    // in-lane bitonic sort ascending (static register indices after unroll)
    #pragma unroll
    for (int k = 2; k <= 32; k <<= 1) {
        #pragma unroll
        for (int j = k >> 1; j > 0; j >>= 1) {
            #pragma unroll
            for (int i = 0; i < 32; i++) {
                const int l = i ^ j;
                if (l > i) {
                    const unsigned lo = umin_(A[i], A[l]);
                    const unsigned hi = umax_(A[i], A[l]);
                    const bool up = ((i & k) == 0);
                    A[i] = up ? lo : hi;
                    A[l] = up ? hi : lo;
                }
            }
        }
    }

    // hypercube merge: after round r, lanes within distance 2^(r+1) hold the
    // identical ascending top-32 of their combined candidates.
    #pragma unroll
    for (int r = 0; r < 6; r++) {
        const int mask = 1 << r;
        // keep lowest-32 of (mine asc ++ partner desc): A[i]=min(A[i],P[31-i]).
        // Pairwise (i,31-i) so both shfls read pre-update values.
        #pragma unroll
        for (int i = 0; i < 16; i++) {
            const unsigned t1 = (unsigned)__shfl_xor((int)A[31-i], mask, 64);
            const unsigned t2 = (unsigned)__shfl_xor((int)A[i],    mask, 64);
            A[i]    = umin_(A[i],    t1);
            A[31-i] = umin_(A[31-i], t2);
        }
        // result is bitonic: in-register bitonic merge -> ascending
        #pragma unroll
        for (int j = 16; j > 0; j >>= 1) {
            #pragma unroll
            for (int i = 0; i < 32; i++) {
                const int l = i ^ j;
                if (l > i) {
                    const unsigned lo = umin_(A[i], A[l]);
                    A[l] = umax_(A[i], A[l]);
                    A[i] = lo;
                }
            }
        }
    }

    // every lane now holds the same ascending top-32; lane<32 needs A[lane]:
    // cndmask halving tree (31 selects, no LDS / shfl).
    #pragma unroll
    for (int s = 16; s >= 1; s >>= 1) {
        #pragma unroll
        for (int i = 0; i < s; i++)
            A[i] = (lane & s) ? A[i+s] : A[i];
    }
    if (lane < 32) idx[(size_t)p*KNBR + lane] = (int)(A[0] & 0x7FFu);
}

// ---------------------------------------------------------------------------
// x1 = lrelu(feat @ W1) : [BN,CIN] -> [BN,64]. 32 points/block, 8/wave.
// s_fT rows stride 36 -> (36j+8w)*4 is 16B-aligned: float4 broadcast reads.
template<int CIN>
__global__ __launch_bounds__(256) void k_unary1(
    const float* __restrict__ feat, const float* __restrict__ w1,
    float* __restrict__ x1)
{
    __shared__ __align__(16) float s_fT[128*36 + 8];
    const int tid = threadIdx.x;
    const int pbase = blockIdx.x * 32;
    for (int i = tid; i < 32*CIN; i += 256) {
        const int p = i / CIN, j = i % CIN;
        s_fT[j*36 + p] = feat[(size_t)pbase*CIN + i];
    }
    __syncthreads();
    const int w = tid >> 6, c = tid & 63;
    const int pb = w * 8;
    float acc[8] = {0.f,0.f,0.f,0.f,0.f,0.f,0.f,0.f};
    for (int j = 0; j < CIN; j++) {
        const float wv = w1[j*64 + c];
        const float4 f0 = *(const float4*)&s_fT[j*36 + pb];
        const float4 f1 = *(const float4*)&s_fT[j*36 + pb + 4];
        acc[0] = fmaf(f0.x, wv, acc[0]); acc[1] = fmaf(f0.y, wv, acc[1]);
        acc[2] = fmaf(f0.z, wv, acc[2]); acc[3] = fmaf(f0.w, wv, acc[3]);
        acc[4] = fmaf(f1.x, wv, acc[4]); acc[5] = fmaf(f1.y, wv, acc[5]);
        acc[6] = fmaf(f1.z, wv, acc[6]); acc[7] = fmaf(f1.w, wv, acc[7]);
    }
    #pragma unroll
    for (int pl = 0; pl < 8; pl++)
        x1[(size_t)(pbase + pb + pl)*64 + c] = lrelu(acc[pl]);
}

// ---------------------------------------------------------------------------
// KPConv, LDS-unioned (~49.3 KB -> 3 blocks/CU), b128 broadcast reads:
//   s_aggT  [0,7680)        : transposed agg, stride 8 (16B rows)
//   region A[7680,11520)    : s_w (ph0-1) -> s_part[2048]+s_featT[8*CIN] (ph2-3)
//   s_x2T   [11520,12032)   : x2 transposed, stride 8
template<int CIN>
__global__ __launch_bounds__(256) void k_kpconv(
    const float* __restrict__ x1, const float4* __restrict__ c4,
    const float* __restrict__ kp,
    const int* __restrict__ idx, const float* __restrict__ feat_in,
    const float* __restrict__ Wk, const float* __restrict__ W2, const float* __restrict__ Ws,
    float* __restrict__ out)
{
    __shared__ __align__(16) float smem[12032];
    __shared__ int   s_idx[256];
    __shared__ float skp[48];
    float* s_aggT = smem;                 // [960*8]
    float* s_w    = smem + 7680;          // [8*480], dead after phase 1
    float* s_part = smem + 7680;          // [4*512], aliases s_w
    float* s_featT= smem + 7680 + 2048;   // [CIN*8] <= 1024, transposed stride 8
    float* s_x2T  = smem + 11520;         // [64*8], transposed stride 8

    const int tid   = threadIdx.x;
    const int pbase = blockIdx.x * 8;
    const int brow  = pbase & ~(N-1);

    if (tid < NKP*3) skp[tid] = kp[tid];
    s_idx[tid] = idx[(size_t)pbase*KNBR + tid];
    __syncthreads();

    // phase 0: kp influence weights (tid -> pl=tid>>5, k=tid&31)
    {
        const int pl = tid >> 5, k = tid & 31;
        const float4 cp = c4[pbase + pl];
        const float4 cn = c4[brow + s_idx[pl*KNBR + k]];
        const float dx = cn.x - cp.x, dy = cn.y - cp.y, dz = cn.z - cp.z;
        #pragma unroll
        for (int K = 0; K < NKP; K++) {
            const float ex = dx - skp[K*3+0], ey = dy - skp[K*3+1], ez = dz - skp[K*3+2];
            const float dist = sqrtf(ex*ex + ey*ey + ez*ez);
            s_w[pl*480 + K*32 + k] = fmaxf(0.f, 1.f - dist*2.f);
        }
    }
    __syncthreads();

    const int w = tid >> 6, lane = tid & 63;
    // phase 1: neighbor aggregation (wave w -> points 2w,2w+1; lane = channel)
    #pragma unroll
    for (int sub = 0; sub < 2; sub++) {
        const int pl = w*2 + sub;
        float ag[NKP];
        #pragma unroll
        for (int K = 0; K < NKP; K++) ag[K] = 0.f;
        const float* wp = &s_w[pl*480];
        for (int k = 0; k < KNBR; k++) {
            const float val = x1[(size_t)(brow + s_idx[pl*KNBR + k])*64 + lane];
            #pragma unroll
            for (int K = 0; K < NKP; K++) ag[K] = fmaf(wp[K*32 + k], val, ag[K]);
        }
        #pragma unroll
        for (int K = 0; K < NKP; K++) s_aggT[(K*64 + lane)*8 + pl] = ag[K];
    }
    __syncthreads();   // s_w dead from here; region A reused

    // s_featT prefetch (transposed, stride 8), overlaps phase 2 compute
    for (int i = tid; i < 8*CIN; i += 256) {
        const int p = i / CIN, j = i % CIN;       // global read coalesced over i
        s_featT[j*8 + p] = feat_in[(size_t)pbase*CIN + i];
    }

    // phase 2: x2 = lrelu(agg @ Wk), split-K: wave w -> j in [240w, 240w+240)
    {
        float acc[8] = {0.f,0.f,0.f,0.f,0.f,0.f,0.f,0.f};
        const int jlo = w * 240, jhi = jlo + 240;
        #pragma unroll 4
        for (int j = jlo; j < jhi; j++) {
            const float wv = Wk[(size_t)j*64 + lane];
            const float4 a0 = *(const float4*)&s_aggT[j*8];
            const float4 a1 = *(const float4*)&s_aggT[j*8 + 4];
            acc[0] = fmaf(a0.x, wv, acc[0]); acc[1] = fmaf(a0.y, wv, acc[1]);
            acc[2] = fmaf(a0.z, wv, acc[2]); acc[3] = fmaf(a0.w, wv, acc[3]);
            acc[4] = fmaf(a1.x, wv, acc[4]); acc[5] = fmaf(a1.y, wv, acc[5]);
            acc[6] = fmaf(a1.z, wv, acc[6]); acc[7] = fmaf(a1.w, wv, acc[7]);
        }
        #pragma unroll
        for (int pl = 0; pl < 8; pl++) s_part[w*512 + pl*64 + lane] = acc[pl];
    }
    __syncthreads();
    for (int i = tid; i < 512; i += 256) {
        const int pl = i >> 6, c = i & 63;
        s_x2T[c*8 + pl] = lrelu(s_part[i] + s_part[512+i] + s_part[1024+i] + s_part[1536+i]);
    }
    __syncthreads();

    // phase 3: out = lrelu(x2@W2 + feat@Ws); wave w -> o in [32w,32w+32),
    // h = lane>>5 splits points; each weight load feeds 4 FMAs via b128 reads.
    {
        const int o = (w << 5) + (lane & 31);
        const int h = lane >> 5;
        float acc[4] = {0.f,0.f,0.f,0.f};
        for (int cc = 0; cc < 64; cc++) {
            const float wv = W2[cc*128 + o];
            const float4 xv = *(const float4*)&s_x2T[cc*8 + h*4];
            acc[0] = fmaf(xv.x, wv, acc[0]); acc[1] = fmaf(xv.y, wv, acc[1]);
            acc[2] = fmaf(xv.z, wv, acc[2]); acc[3] = fmaf(xv.w, wv, acc[3]);
        }
        for (int j = 0; j < CIN; j++) {
            const float wv = Ws[j*128 + o];
            const float4 fv = *(const float4*)&s_featT[j*8 + h*4];
            acc[0] = fmaf(fv.x, wv, acc[0]); acc[1] = fmaf(fv.y, wv, acc[1]);
            acc[2] = fmaf(fv.z, wv, acc[2]); acc[3] = fmaf(fv.w, wv, acc[3]);
        }
        #pragma unroll
        for (int pi = 0; pi < 4; pi++)
            out[(size_t)(pbase + h*4 + pi)*128 + o] = lrelu(acc[pi]);
    }
}

// ---------------------------------------------------------------------------
// VLAD assignment: a = softmax(f @ wa) * valid; also accumulates sum_a[b,kc].
__global__ __launch_bounds__(256) void k_vlad_a(
    const float* __restrict__ f, const float* __restrict__ wa,
    const int* __restrict__ m, float* __restrict__ a, float* __restrict__ sumA)
{
    __shared__ __align__(16) float s_fT[128*36 + 8];
    __shared__ float s_m[32];
    const int tid = threadIdx.x;
    const int pbase = blockIdx.x * 32;
    const int b = pbase >> 11;
    for (int i = tid; i < 32*128; i += 256) {
        const int p = i >> 7, j = i & 127;
        s_fT[j*36 + p] = f[(size_t)pbase*128 + i];
    }
    if (tid < 32) s_m[tid] = (m[pbase + tid] != 0) ? 0.f : 1.f;
    __syncthreads();
    const int w = tid >> 6, kc = tid & 63;
    const int pb = w * 8;
    float acc[8] = {0.f,0.f,0.f,0.f,0.f,0.f,0.f,0.f};
    for (int j = 0; j < 128; j++) {
        const float wv = wa[j*64 + kc];
        const float4 f0 = *(const float4*)&s_fT[j*36 + pb];
        const float4 f1 = *(const float4*)&s_fT[j*36 + pb + 4];
        acc[0] = fmaf(f0.x, wv, acc[0]); acc[1] = fmaf(f0.y, wv, acc[1]);
        acc[2] = fmaf(f0.z, wv, acc[2]); acc[3] = fmaf(f0.w, wv, acc[3]);
        acc[4] = fmaf(f1.x, wv, acc[4]); acc[5] = fmaf(f1.y, wv, acc[5]);
        acc[6] = fmaf(f1.z, wv, acc[6]); acc[7] = fmaf(f1.w, wv, acc[7]);
    }
    float part = 0.f;
    #pragma unroll
    for (int pl = 0; pl < 8; pl++) {
        float mx = acc[pl];
        #pragma unroll
        for (int off = 32; off > 0; off >>= 1) mx = fmaxf(mx, __shfl_xor(mx, off, 64));
        const float e = expf(acc[pl] - mx);
        float se = e;
        #pragma unroll
        for (int off = 32; off > 0; off >>= 1) se += __shfl_xor(se, off, 64);
        const float av = (e / se) * s_m[pb + pl];
        a[(size_t)(pbase + pb + pl)*64 + kc] = av;
        part += av;
    }
    atomicAdd(&sumA[b*64 + kc], part);
}

// ---------------------------------------------------------------------------
// VLAD accumulation: vpart[ch][b][kc][d] = sum_{n in chunk} a[b,n,kc]*f[b,n,d]
// grid = B*VCH blocks, 256 threads, 8x4 register tile, float4 LDS reads.
__global__ __launch_bounds__(256) void k_vlad_acc(
    const float* __restrict__ a, const float* __restrict__ f,
    float* __restrict__ vpart)
{
    __shared__ __align__(16) float s_a[32*64];
    __shared__ __align__(16) float s_f[32*128];
    const int b  = blockIdx.x >> 4;          // VCH = 16
    const int ch = blockIdx.x & 15;
    const int n0 = ch * (N / VCH);           // 128 points per chunk
    const int tid = threadIdx.x;
    const int kc0 = (tid >> 5) * 8;
    const int d0  = (tid & 31) * 4;
    float acc[8][4];
    #pragma unroll
    for (int i = 0; i < 8; i++)
        #pragma unroll
        for (int j = 0; j < 4; j++) acc[i][j] = 0.f;
    for (int t = 0; t < N/VCH; t += 32) {
        __syncthreads();
        const size_t base = (size_t)(b*N + n0 + t);
        for (int i = tid; i < 32*64; i += 256)  s_a[i] = a[(base << 6) + i];
        for (int i = tid; i < 32*128; i += 256) s_f[i] = f[(base << 7) + i];
        __syncthreads();
        for (int n = 0; n < 32; n++) {
            const float4 a0 = *(const float4*)&s_a[n*64 + kc0];
            const float4 a1 = *(const float4*)&s_a[n*64 + kc0 + 4];
            const float4 fv = *(const float4*)&s_f[n*128 + d0];
            const float av[8] = {a0.x,a0.y,a0.z,a0.w,a1.x,a1.y,a1.z,a1.w};
            const float fw[4] = {fv.x,fv.y,fv.z,fv.w};
            #pragma unroll
            for (int i = 0; i < 8; i++)
                #pragma unroll
                for (int j = 0; j < 4; j++) acc[i][j] = fmaf(av[i], fw[j], acc[i][j]);
        }
    }
    float* vp = vpart + ((size_t)ch*B + b)*8192;
    #pragma unroll
    for (int i = 0; i < 8; i++)
        #pragma unroll
        for (int j = 0; j < 4; j++) vp[(kc0+i)*128 + d0 + j] = acc[i][j];
}

// ---------------------------------------------------------------------------
// Reduce partials, subtract suma*centers, intra-normalize.
__global__ __launch_bounds__(128) void k_vlad_norm(
    const float* __restrict__ vpart, const float* __restrict__ sumA,
    const float* __restrict__ centers, float* __restrict__ v)
{
    const int b = blockIdx.x >> 6, kc = blockIdx.x & 63, d = threadIdx.x;
    float acc = 0.f;
    #pragma unroll
    for (int c = 0; c < VCH; c++)
        acc += vpart[((size_t)c*B + b)*8192 + kc*128 + d];
    const float vv = acc - sumA[b*64 + kc] * centers[kc*128 + d];
    float s2 = vv*vv;
    #pragma unroll
    for (int off = 32; off > 0; off >>= 1) s2 += __shfl_xor(s2, off, 64);
    __shared__ float red[2];
    if ((d & 63) == 0) red[d >> 6] = s2;
    __syncthreads();
    const float tot = red[0] + red[1];
    v[((size_t)b*64 + kc)*128 + d] = vv / (sqrtf(tot) + 1e-8f);
}

// global-norm scale per batch: scale[b] = 1/(||v_b||+1e-8)
__global__ __launch_bounds__(256) void k_vnorm(
    const float* __restrict__ v, float* __restrict__ scale)
{
    const int b = blockIdx.x;
    float s = 0.f;
    for (int i = threadIdx.x; i < 8192; i += 256) { const float t = v[(size_t)b*8192 + i]; s = fmaf(t, t, s); }
    #pragma unroll
    for (int off = 32; off > 0; off >>= 1) s += __shfl_xor(s, off, 64);
    __shared__ float red[4];
    if ((threadIdx.x & 63) == 0) red[threadIdx.x >> 6] = s;
    __syncthreads();
    if (threadIdx.x == 0) {
        const float tot = red[0] + red[1] + red[2] + red[3];
        scale[b] = 1.f / (sqrtf(tot) + 1e-8f);
    }
}

__global__ __launch_bounds__(256) void k_zero(float* __restrict__ p, int n)
{
    const int i = blockIdx.x * 256 + threadIdx.x;
    if (i < n) p[i] = 0.f;
}

// projection: 32 j-chunk blocks, loop all batches; proj fetched exactly once.
__global__ __launch_bounds__(256) void k_proj(
    const float* __restrict__ v, const float* __restrict__ scale,
    const float* __restrict__ proj, float* __restrict__ outacc)
{
    __shared__ __align__(16) float s_v[8*256];
    __shared__ float s_sc[8];
    const int jc = blockIdx.x, o = threadIdx.x;
    const int j0 = jc * 256;
    for (int i = o; i < 8*256; i += 256) {
        const int bb = i >> 8, jj = i & 255;
        s_v[i] = v[(size_t)bb*8192 + j0 + jj];
    }
    if (o < 8) s_sc[o] = scale[o];
    __syncthreads();
    float acc[8] = {0.f,0.f,0.f,0.f,0.f,0.f,0.f,0.f};
    for (int jj = 0; jj < 256; jj += 4) {
        float pv[4];
        #pragma unroll
        for (int q = 0; q < 4; q++) pv[q] = proj[(size_t)(j0+jj+q)*256 + o];
        #pragma unroll
        for (int bb = 0; bb < 8; bb++) {
            const float4 vv = *(const float4*)&s_v[bb*256 + jj];
            acc[bb] = fmaf(vv.x, pv[0], acc[bb]);
            acc[bb] = fmaf(vv.y, pv[1], acc[bb]);
            acc[bb] = fmaf(vv.z, pv[2], acc[bb]);
            acc[bb] = fmaf(vv.w, pv[3], acc[bb]);
        }
    }
    #pragma unroll
    for (int bb = 0; bb < 8; bb++) atomicAdd(&outacc[bb*256 + o], acc[bb] * s_sc[bb]);
}

// final L2 normalize + f32 store
__global__ __launch_bounds__(256) void k_outnorm(
    const float* __restrict__ outacc, float* __restrict__ out)
{
    const int b = blockIdx.x, o = threadIdx.x;
    const float val = outacc[b*256 + o];
    float s = val*val;
    #pragma unroll
    for (int off = 32; off > 0; off >>= 1) s += __shfl_xor(s, off, 64);
    __shared__ float red[4];
    if ((o & 63) == 0) red[o >> 6] = s;
    __syncthreads();
    const float tot = red[0] + red[1] + red[2] + red[3];
    out[b*256 + o] = val / (sqrtf(tot) + 1e-12f);
}

// ---------------------------------------------------------------------------
extern "C" void kernel_launch(void* const* d_in, const int* in_sizes, int n_in,
                              void* d_out, int out_size, void* d_ws, size_t ws_size,
                              hipStream_t stream)
{
    (void)in_sizes; (void)n_in; (void)out_size; (void)ws_size;
    const float* x     = (const float*)d_in[0];
    const int*   m     = (const int*)  d_in[1];
    const float* pn_w1 = (const float*)d_in[2];
    const float* pn_b1 = (const float*)d_in[3];
    const float* pn_w2 = (const float*)d_in[4];
    const float* pn_b2 = (const float*)d_in[5];
    const float* kp    = (const float*)d_in[6];
    const float* bw1[3] = {(const float*)d_in[7],  (const float*)d_in[11], (const float*)d_in[15]};
    const float* bwk[3] = {(const float*)d_in[8],  (const float*)d_in[12], (const float*)d_in[16]};
    const float* bw2[3] = {(const float*)d_in[9],  (const float*)d_in[13], (const float*)d_in[17]};
    const float* bws[3] = {(const float*)d_in[10], (const float*)d_in[14], (const float*)d_in[18]};
    const float* vlad_wa      = (const float*)d_in[19];
    const float* vlad_centers = (const float*)d_in[20];
    const float* vlad_proj    = (const float*)d_in[21];
    float* out = (float*)d_out;

    char* ws = (char*)d_ws;
    size_t off = 0;
    auto alloc = [&](size_t bytes) -> void* {
        void* p = ws + off;
        off = (off + bytes + 255) & ~(size_t)255;
        return p;
    };
    float4* coords4 = (float4*)alloc((size_t)BN*16);      //  0.26 MB
    float*  feat0   = (float*)alloc((size_t)BN*64*4);     //  4.19 MB
    int*    idxb    = (int*)  alloc((size_t)BN*KNBR*4);   //  2.10 MB
    float*  x1b     = (float*)alloc((size_t)BN*64*4);     //  4.19 MB (aliased by vpart)
    float*  fA      = (float*)alloc((size_t)BN*128*4);    //  8.39 MB
    float*  fB      = (float*)alloc((size_t)BN*128*4);    //  8.39 MB
    float*  abuf    = (float*)alloc((size_t)BN*64*4);     //  4.19 MB
    float*  vbuf    = (float*)alloc((size_t)B*8192*4);    //  0.26 MB
    float*  scaleb  = (float*)alloc((size_t)B*4);
    float*  sumA    = (float*)alloc((size_t)B*64*4);      // contiguous with outacc
    float*  outacc  = (float*)alloc((size_t)B*256*4);
    float*  vpart   = x1b;  // VCH*B*8192*4 = 4.19 MB; x1b dead after last kpconv

    k_zero<<<(B*64 + B*256 + 255)/256, 256, 0, stream>>>(sumA, B*64 + B*256);
    k_pointnet<<<BN/32, 256, 0, stream>>>(x, m, pn_w1, pn_b1, pn_w2, pn_b2, feat0, coords4);
    k_knn<<<BN/4, 256, 0, stream>>>(coords4, idxb);

    k_unary1<64> <<<BN/32, 256, 0, stream>>>(feat0, bw1[0], x1b);
    k_kpconv<64> <<<BN/8, 256, 0, stream>>>(x1b, coords4, kp, idxb, feat0, bwk[0], bw2[0], bws[0], fA);
    k_unary1<128><<<BN/32, 256, 0, stream>>>(fA, bw1[1], x1b);
    k_kpconv<128><<<BN/8, 256, 0, stream>>>(x1b, coords4, kp, idxb, fA, bwk[1], bw2[1], bws[1], fB);
    k_unary1<128><<<BN/32, 256, 0, stream>>>(fB, bw1[2], x1b);
    k_kpconv<128><<<BN/8, 256, 0, stream>>>(x1b, coords4, kp, idxb, fB, bwk[2], bw2[2], bws[2], fA);

    k_vlad_a<<<BN/32, 256, 0, stream>>>(fA, vlad_wa, m, abuf, sumA);
    k_vlad_acc<<<B*VCH, 256, 0, stream>>>(abuf, fA, vpart);
    k_vlad_norm<<<B*64, 128, 0, stream>>>(vpart, sumA, vlad_centers, vbuf);
    k_vnorm<<<B, 256, 0, stream>>>(vbuf, scaleb);
    k_proj<<<32, 256, 0, stream>>>(vbuf, scaleb, vlad_proj, outacc);
    k_outnorm<<<B, 256, 0, stream>>>(outacc, out);
}

// Round 8
// 542.473 us; speedup vs baseline: 2.4908x; 1.1507x over previous
//
#include <hip/hip_runtime.h>
#include <hip/hip_bf16.h>

#define B 8
#define N 2048
#define BN (B*N)
#define KNBR 32
#define NKP 15
#define VCH 16   // n-chunks per batch in VLAD accumulation

__device__ __forceinline__ float lrelu(float x){ return x > 0.f ? x : 0.1f*x; }
__device__ __forceinline__ unsigned umin_(unsigned a, unsigned b){ return a < b ? a : b; }
__device__ __forceinline__ unsigned umax_(unsigned a, unsigned b){ return a < b ? b : a; }

// MFMA fragment types (per guide: short8 = 8 bf16 = 4 VGPRs)
typedef __attribute__((ext_vector_type(8))) short bf16x8;
typedef __attribute__((ext_vector_type(4))) float fx4;

__device__ __forceinline__ short bfr(float f){
    union { __hip_bfloat16 h; short s; } u;
    u.h = __float2bfloat16(f);
    return u.s;
}
__device__ __forceinline__ bf16x8 to_bf8(fx4 lo, fx4 hi){
    bf16x8 r;
    r[0]=bfr(lo.x); r[1]=bfr(lo.y); r[2]=bfr(lo.z); r[3]=bfr(lo.w);
    r[4]=bfr(hi.x); r[5]=bfr(hi.y); r[6]=bfr(hi.z); r[7]=bfr(hi.w);
    return r;
}

// ---------------------------------------------------------------------------
// Weight prep: WkT[n][k] = bf16(Wk[k][n])  (n<64, k<960)
__global__ __launch_bounds__(256) void k_prep_wkT(
    const float* __restrict__ wk, short* __restrict__ wkT)
{
    const int i = blockIdx.x * 256 + threadIdx.x;
    if (i < 64*960) {
        const int n = i / 960, k = i % 960;
        wkT[i] = bfr(wk[k*64 + n]);
    }
}
// WcatT[n][k] = bf16( k<64 ? W2[k][n] : Ws[k-64][n] )  (n<128, k<KC)
template<int KC>
__global__ __launch_bounds__(256) void k_prep_catT(
    const float* __restrict__ w2, const float* __restrict__ ws_, short* __restrict__ catT)
{
    const int i = blockIdx.x * 256 + threadIdx.x;
    if (i < 128*KC) {
        const int n = i / KC, k = i % KC;
        catT[i] = bfr(k < 64 ? w2[k*128 + n] : ws_[(k-64)*128 + n]);
    }
}

// ---------------------------------------------------------------------------
// PointNet: f = relu(relu(x@W1+b1)@W2+b2); emits coords4 = (masked xyz, sq).
__global__ __launch_bounds__(256) void k_pointnet(
    const float* __restrict__ x, const int* __restrict__ m,
    const float* __restrict__ w1, const float* __restrict__ b1,
    const float* __restrict__ w2, const float* __restrict__ b2,
    float* __restrict__ feat, float4* __restrict__ coords4)
{
    __shared__ float s_x[32][3];
    __shared__ __align__(16) float s_hT[64*40];
    const int tid = threadIdx.x;
    const int pbase = blockIdx.x * 32;
    if (tid < 32) {
        const int p = pbase + tid;
        const float x0 = x[p*3+0], x1v = x[p*3+1], x2v = x[p*3+2];
        s_x[tid][0] = x0; s_x[tid][1] = x1v; s_x[tid][2] = x2v;
        const bool mm = (m[p] != 0);
        const float cx = mm ? 1e6f : x0, cy = mm ? 1e6f : x1v, cz = mm ? 1e6f : x2v;
        coords4[p] = make_float4(cx, cy, cz, cx*cx + cy*cy + cz*cz);
    }
    __syncthreads();
    const int w = tid >> 6, c = tid & 63;
    const int pb = w * 8;
    {
        const float w10 = w1[c], w11 = w1[64+c], w12 = w1[128+c], bb = b1[c];
        #pragma unroll
        for (int pl = 0; pl < 8; pl++) {
            float s = bb;
            s = fmaf(s_x[pb+pl][0], w10, s);
            s = fmaf(s_x[pb+pl][1], w11, s);
            s = fmaf(s_x[pb+pl][2], w12, s);
            s_hT[c*40 + pb + pl] = fmaxf(s, 0.f);
        }
    }
    {
        float acc[8];
        const float bb = b2[c];
        #pragma unroll
        for (int pl = 0; pl < 8; pl++) acc[pl] = bb;
        for (int j = 0; j < 64; j++) {
            const float wv = w2[j*64 + c];
            const float4 h0 = *(const float4*)&s_hT[j*40 + pb];
            const float4 h1 = *(const float4*)&s_hT[j*40 + pb + 4];
            acc[0] = fmaf(h0.x, wv, acc[0]); acc[1] = fmaf(h0.y, wv, acc[1]);
            acc[2] = fmaf(h0.z, wv, acc[2]); acc[3] = fmaf(h0.w, wv, acc[3]);
            acc[4] = fmaf(h1.x, wv, acc[4]); acc[5] = fmaf(h1.y, wv, acc[5]);
            acc[6] = fmaf(h1.z, wv, acc[6]); acc[7] = fmaf(h1.w, wv, acc[7]);
        }
        #pragma unroll
        for (int pl = 0; pl < 8; pl++)
            feat[(size_t)(pbase + pb + pl)*64 + c] = fmaxf(acc[pl], 0.f);
    }
}

// ---------------------------------------------------------------------------
// KNN: in-lane sorted runs + hypercube merge (round-7 verified).
__global__ __launch_bounds__(256) void k_knn(
    const float4* __restrict__ c4, int* __restrict__ idx)
{
    __shared__ float4 s_c[N];
    const int tid = threadIdx.x;
    const int w = tid >> 6, lane = tid & 63;
    const int p = blockIdx.x * 4 + w;
    const int b = p >> 11;
    for (int i = tid; i < N; i += 256) s_c[i] = c4[(size_t)b*N + i];
    __syncthreads();
    const float4 me = s_c[p & (N-1)];

    unsigned A[32];
    #pragma unroll
    for (int j = 0; j < 32; j++) {
        const float4 s = s_c[j*64 + lane];
        float d2 = me.w + s.w - 2.f*(me.x*s.x + me.y*s.y + me.z*s.z);
        d2 = fmaxf(d2, 0.f);
        A[j] = (__float_as_uint(d2) & 0xFFFFF800u) | (unsigned)(j*64 + lane);
    }
    #pragma unroll
    for (int k = 2; k <= 32; k <<= 1) {
        #pragma unroll
        for (int j = k >> 1; j > 0; j >>= 1) {
            #pragma unroll
            for (int i = 0; i < 32; i++) {
                const int l = i ^ j;
                if (l > i) {
                    const unsigned lo = umin_(A[i], A[l]);
                    const unsigned hi = umax_(A[i], A[l]);
                    const bool up = ((i & k) == 0);
                    A[i] = up ? lo : hi;
                    A[l] = up ? hi : lo;
                }
            }
        }
    }
    #pragma unroll
    for (int r = 0; r < 6; r++) {
        const int mask = 1 << r;
        #pragma unroll
        for (int i = 0; i < 16; i++) {
            const unsigned t1 = (unsigned)__shfl_xor((int)A[31-i], mask, 64);
            const unsigned t2 = (unsigned)__shfl_xor((int)A[i],    mask, 64);
            A[i]    = umin_(A[i],    t1);
            A[31-i] = umin_(A[31-i], t2);
        }
        #pragma unroll
        for (int j = 16; j > 0; j >>= 1) {
            #pragma unroll
            for (int i = 0; i < 32; i++) {
                const int l = i ^ j;
                if (l > i) {
                    const unsigned lo = umin_(A[i], A[l]);
                    A[l] = umax_(A[i], A[l]);
                    A[i] = lo;
                }
            }
        }
    }
    #pragma unroll
    for (int s = 16; s >= 1; s >>= 1) {
        #pragma unroll
        for (int i = 0; i < s; i++)
            A[i] = (lane & s) ? A[i+s] : A[i];
    }
    if (lane < 32) idx[(size_t)p*KNBR + lane] = (int)(A[0] & 0x7FFu);
}

// ---------------------------------------------------------------------------
// x1 = lrelu(feat @ W1) : [BN,CIN] -> [BN,64]. 32 points/block, 8/wave.
template<int CIN>
__global__ __launch_bounds__(256) void k_unary1(
    const float* __restrict__ feat, const float* __restrict__ w1,
    float* __restrict__ x1)
{
    __shared__ __align__(16) float s_fT[128*36 + 8];
    const int tid = threadIdx.x;
    const int pbase = blockIdx.x * 32;
    for (int i = tid; i < 32*CIN; i += 256) {
        const int p = i / CIN, j = i % CIN;
        s_fT[j*36 + p] = feat[(size_t)pbase*CIN + i];
    }
    __syncthreads();
    const int w = tid >> 6, c = tid & 63;
    const int pb = w * 8;
    float acc[8] = {0.f,0.f,0.f,0.f,0.f,0.f,0.f,0.f};
    for (int j = 0; j < CIN; j++) {
        const float wv = w1[j*64 + c];
        const float4 f0 = *(const float4*)&s_fT[j*36 + pb];
        const float4 f1 = *(const float4*)&s_fT[j*36 + pb + 4];
        acc[0] = fmaf(f0.x, wv, acc[0]); acc[1] = fmaf(f0.y, wv, acc[1]);
        acc[2] = fmaf(f0.z, wv, acc[2]); acc[3] = fmaf(f0.w, wv, acc[3]);
        acc[4] = fmaf(f1.x, wv, acc[4]); acc[5] = fmaf(f1.y, wv, acc[5]);
        acc[6] = fmaf(f1.z, wv, acc[6]); acc[7] = fmaf(f1.w, wv, acc[7]);
    }
    #pragma unroll
    for (int pl = 0; pl < 8; pl++)
        x1[(size_t)(pbase + pb + pl)*64 + c] = lrelu(acc[pl]);
}

// ---------------------------------------------------------------------------
// KPConv with MFMA phases 2+3. 8 points/block (M=8 padded into M=16 tiles).
// LDS (~47.4 KB, 3 blocks/CU):
//   s_agg  f32 [8][964]  (row pad 4: conflict-free b128 A-reads)
//   union  [3840 floats]: s_w [8][480] (ph0-1) -> s_x2f [8][68] + s_featf [8][CIN+4]
template<int CIN>
__global__ __launch_bounds__(256) void k_kpconv(
    const float* __restrict__ x1, const float4* __restrict__ c4,
    const float* __restrict__ kp,
    const int* __restrict__ idx, const float* __restrict__ feat_in,
    const short* __restrict__ WkT, const short* __restrict__ WcatT,
    float* __restrict__ out)
{
    constexpr int KC = 64 + CIN;   // phase-3 K extent
    constexpr int FS = CIN + 4;    // featf row stride
    __shared__ __align__(16) float smem[7712 + 3840];
    __shared__ int   s_idx[256];
    __shared__ float skp[48];
    float* s_agg   = smem;                 // [8*964]
    float* s_w     = smem + 7712;          // [8*480], dead after ph1
    float* s_x2f   = smem + 7712;          // [8*68]
    float* s_featf = smem + 7712 + 544;    // [8*FS]

    const int tid   = threadIdx.x;
    const int pbase = blockIdx.x * 8;
    const int brow  = pbase & ~(N-1);

    if (tid < NKP*3) skp[tid] = kp[tid];
    s_idx[tid] = idx[(size_t)pbase*KNBR + tid];
    __syncthreads();

    // phase 0: kp influence weights (tid -> pl=tid>>5, k=tid&31)
    {
        const int pl = tid >> 5, k = tid & 31;
        const float4 cp = c4[pbase + pl];
        const float4 cn = c4[brow + s_idx[pl*KNBR + k]];
        const float dx = cn.x - cp.x, dy = cn.y - cp.y, dz = cn.z - cp.z;
        #pragma unroll
        for (int K = 0; K < NKP; K++) {
            const float ex = dx - skp[K*3+0], ey = dy - skp[K*3+1], ez = dz - skp[K*3+2];
            const float dist = sqrtf(ex*ex + ey*ey + ez*ez);
            s_w[pl*480 + K*32 + k] = fmaxf(0.f, 1.f - dist*2.f);
        }
    }
    __syncthreads();

    const int w = tid >> 6, lane = tid & 63;
    // phase 1: neighbor aggregation; row-major agg writes (conflict-free)
    #pragma unroll
    for (int sub = 0; sub < 2; sub++) {
        const int pl = w*2 + sub;
        float ag[NKP];
        #pragma unroll
        for (int K = 0; K < NKP; K++) ag[K] = 0.f;
        const float* wp = &s_w[pl*480];
        for (int k = 0; k < KNBR; k++) {
            const float val = x1[(size_t)(brow + s_idx[pl*KNBR + k])*64 + lane];
            #pragma unroll
            for (int K = 0; K < NKP; K++) ag[K] = fmaf(wp[K*32 + k], val, ag[K]);
        }
        #pragma unroll
        for (int K = 0; K < NKP; K++) s_agg[pl*964 + K*64 + lane] = ag[K];
    }
    __syncthreads();   // s_w dead; union region becomes x2f/featf

    // stage feat (f32) into featf rows
    for (int i = tid; i < 8*CIN; i += 256) {
        const int p = i / CIN, j = i % CIN;
        s_featf[p*FS + j] = feat_in[(size_t)pbase*CIN + i];
    }

    const int nlane = lane & 15, q = lane >> 4;
    // phase 2: x2 = lrelu(agg @ Wk) via MFMA. Wave w -> cols [16w,16w+16).
    // A[m][k]: m=lane&15 (pt = m&7), k = q*8+j.  B[k][n]: n=lane&15, k=q*8+j.
    {
        fx4 acc = {0.f,0.f,0.f,0.f};
        const float* arow = &s_agg[(nlane & 7)*964];
        const short* brw  = &WkT[(size_t)(w*16 + nlane)*960];
        for (int t = 0; t < 30; t++) {
            const int k0 = t*32 + q*8;
            const fx4 lo = *(const fx4*)&arow[k0];
            const fx4 hi = *(const fx4*)&arow[k0+4];
            const bf16x8 af = to_bf8(lo, hi);
            const bf16x8 bf = *(const bf16x8*)&brw[k0];
            acc = __builtin_amdgcn_mfma_f32_16x16x32_bf16(af, bf, acc, 0, 0, 0);
        }
        if (q < 2) {           // rows 8-15 are duplicates of 0-7
            #pragma unroll
            for (int r = 0; r < 4; r++)
                s_x2f[(q*4+r)*68 + w*16 + nlane] = lrelu(acc[r]);
        }
    }
    __syncthreads();

    // phase 3: out = lrelu([x2|feat] @ [W2;Ws]) via MFMA. Wave w -> cols
    // [32w,32w+32) as two 16-col tiles; K = 64+CIN in KC/32 steps.
    {
        fx4 acc0 = {0.f,0.f,0.f,0.f}, acc1 = {0.f,0.f,0.f,0.f};
        const short* b0r = &WcatT[(size_t)(w*32 + nlane)*KC];
        const short* b1r = &WcatT[(size_t)(w*32 + 16 + nlane)*KC];
        const int pt = nlane & 7;
        #pragma unroll
        for (int t = 0; t < KC/32; t++) {
            const int k0 = t*32 + q*8;
            const float* src = (t < 2) ? &s_x2f[pt*68 + k0] : &s_featf[pt*FS + (k0 - 64)];
            const fx4 lo = *(const fx4*)&src[0];
            const fx4 hi = *(const fx4*)&src[4];
            const bf16x8 af = to_bf8(lo, hi);
            const bf16x8 b0 = *(const bf16x8*)&b0r[k0];
            const bf16x8 b1 = *(const bf16x8*)&b1r[k0];
            acc0 = __builtin_amdgcn_mfma_f32_16x16x32_bf16(af, b0, acc0, 0, 0, 0);
            acc1 = __builtin_amdgcn_mfma_f32_16x16x32_bf16(af, b1, acc1, 0, 0, 0);
        }
        if (q < 2) {
            #pragma unroll
            for (int r = 0; r < 4; r++) {
                const size_t p = (size_t)(pbase + q*4 + r)*128;
                out[p + w*32 + nlane]      = lrelu(acc0[r]);
                out[p + w*32 + 16 + nlane] = lrelu(acc1[r]);
            }
        }
    }
}

// ---------------------------------------------------------------------------
// VLAD assignment: a = softmax(f @ wa) * valid; also accumulates sum_a[b,kc].
__global__ __launch_bounds__(256) void k_vlad_a(
    const float* __restrict__ f, const float* __restrict__ wa,
    const int* __restrict__ m, float* __restrict__ a, float* __restrict__ sumA)
{
    __shared__ __align__(16) float s_fT[128*36 + 8];
    __shared__ float s_m[32];
    const int tid = threadIdx.x;
    const int pbase = blockIdx.x * 32;
    const int b = pbase >> 11;
    for (int i = tid; i < 32*128; i += 256) {
        const int p = i >> 7, j = i & 127;
        s_fT[j*36 + p] = f[(size_t)pbase*128 + i];
    }
    if (tid < 32) s_m[tid] = (m[pbase + tid] != 0) ? 0.f : 1.f;
    __syncthreads();
    const int w = tid >> 6, kc = tid & 63;
    const int pb = w * 8;
    float acc[8] = {0.f,0.f,0.f,0.f,0.f,0.f,0.f,0.f};
    for (int j = 0; j < 128; j++) {
        const float wv = wa[j*64 + kc];
        const float4 f0 = *(const float4*)&s_fT[j*36 + pb];
        const float4 f1 = *(const float4*)&s_fT[j*36 + pb + 4];
        acc[0] = fmaf(f0.x, wv, acc[0]); acc[1] = fmaf(f0.y, wv, acc[1]);
        acc[2] = fmaf(f0.z, wv, acc[2]); acc[3] = fmaf(f0.w, wv, acc[3]);
        acc[4] = fmaf(f1.x, wv, acc[4]); acc[5] = fmaf(f1.y, wv, acc[5]);
        acc[6] = fmaf(f1.z, wv, acc[6]); acc[7] = fmaf(f1.w, wv, acc[7]);
    }
    float part = 0.f;
    #pragma unroll
    for (int pl = 0; pl < 8; pl++) {
        float mx = acc[pl];
        #pragma unroll
        for (int off = 32; off > 0; off >>= 1) mx = fmaxf(mx, __shfl_xor(mx, off, 64));
        const float e = expf(acc[pl] - mx);
        float se = e;
        #pragma unroll
        for (int off = 32; off > 0; off >>= 1) se += __shfl_xor(se, off, 64);
        const float av = (e / se) * s_m[pb + pl];
        a[(size_t)(pbase + pb + pl)*64 + kc] = av;
        part += av;
    }
    atomicAdd(&sumA[b*64 + kc], part);
}

// ---------------------------------------------------------------------------
__global__ __launch_bounds__(256) void k_vlad_acc(
    const float* __restrict__ a, const float* __restrict__ f,
    float* __restrict__ vpart)
{
    __shared__ __align__(16) float s_a[32*64];
    __shared__ __align__(16) float s_f[32*128];
    const int b  = blockIdx.x >> 4;
    const int ch = blockIdx.x & 15;
    const int n0 = ch * (N / VCH);
    const int tid = threadIdx.x;
    const int kc0 = (tid >> 5) * 8;
    const int d0  = (tid & 31) * 4;
    float acc[8][4];
    #pragma unroll
    for (int i = 0; i < 8; i++)
        #pragma unroll
        for (int j = 0; j < 4; j++) acc[i][j] = 0.f;
    for (int t = 0; t < N/VCH; t += 32) {
        __syncthreads();
        const size_t base = (size_t)(b*N + n0 + t);
        for (int i = tid; i < 32*64; i += 256)  s_a[i] = a[(base << 6) + i];
        for (int i = tid; i < 32*128; i += 256) s_f[i] = f[(base << 7) + i];
        __syncthreads();
        for (int n = 0; n < 32; n++) {
            const float4 a0 = *(const float4*)&s_a[n*64 + kc0];
            const float4 a1 = *(const float4*)&s_a[n*64 + kc0 + 4];
            const float4 fv = *(const float4*)&s_f[n*128 + d0];
            const float av[8] = {a0.x,a0.y,a0.z,a0.w,a1.x,a1.y,a1.z,a1.w};
            const float fw[4] = {fv.x,fv.y,fv.z,fv.w};
            #pragma unroll
            for (int i = 0; i < 8; i++)
                #pragma unroll
                for (int j = 0; j < 4; j++) acc[i][j] = fmaf(av[i], fw[j], acc[i][j]);
        }
    }
    float* vp = vpart + ((size_t)ch*B + b)*8192;
    #pragma unroll
    for (int i = 0; i < 8; i++)
        #pragma unroll
        for (int j = 0; j < 4; j++) vp[(kc0+i)*128 + d0 + j] = acc[i][j];
}

// ---------------------------------------------------------------------------
__global__ __launch_bounds__(128) void k_vlad_norm(
    const float* __restrict__ vpart, const float* __restrict__ sumA,
    const float* __restrict__ centers, float* __restrict__ v)
{
    const int b = blockIdx.x >> 6, kc = blockIdx.x & 63, d = threadIdx.x;
    float acc = 0.f;
    #pragma unroll
    for (int c = 0; c < VCH; c++)
        acc += vpart[((size_t)c*B + b)*8192 + kc*128 + d];
    const float vv = acc - sumA[b*64 + kc] * centers[kc*128 + d];
    float s2 = vv*vv;
    #pragma unroll
    for (int off = 32; off > 0; off >>= 1) s2 += __shfl_xor(s2, off, 64);
    __shared__ float red[2];
    if ((d & 63) == 0) red[d >> 6] = s2;
    __syncthreads();
    const float tot = red[0] + red[1];
    v[((size_t)b*64 + kc)*128 + d] = vv / (sqrtf(tot) + 1e-8f);
}

__global__ __launch_bounds__(256) void k_vnorm(
    const float* __restrict__ v, float* __restrict__ scale)
{
    const int b = blockIdx.x;
    float s = 0.f;
    for (int i = threadIdx.x; i < 8192; i += 256) { const float t = v[(size_t)b*8192 + i]; s = fmaf(t, t, s); }
    #pragma unroll
    for (int off = 32; off > 0; off >>= 1) s += __shfl_xor(s, off, 64);
    __shared__ float red[4];
    if ((threadIdx.x & 63) == 0) red[threadIdx.x >> 6] = s;
    __syncthreads();
    if (threadIdx.x == 0) {
        const float tot = red[0] + red[1] + red[2] + red[3];
        scale[b] = 1.f / (sqrtf(tot) + 1e-8f);
    }
}

__global__ __launch_bounds__(256) void k_zero(float* __restrict__ p, int n)
{
    const int i = blockIdx.x * 256 + threadIdx.x;
    if (i < n) p[i] = 0.f;
}

__global__ __launch_bounds__(256) void k_proj(
    const float* __restrict__ v, const float* __restrict__ scale,
    const float* __restrict__ proj, float* __restrict__ outacc)
{
    __shared__ __align__(16) float s_v[8*256];
    __shared__ float s_sc[8];
    const int jc = blockIdx.x, o = threadIdx.x;
    const int j0 = jc * 256;
    for (int i = o; i < 8*256; i += 256) {
        const int bb = i >> 8, jj = i & 255;
        s_v[i] = v[(size_t)bb*8192 + j0 + jj];
    }
    if (o < 8) s_sc[o] = scale[o];
    __syncthreads();
    float acc[8] = {0.f,0.f,0.f,0.f,0.f,0.f,0.f,0.f};
    for (int jj = 0; jj < 256; jj += 4) {
        float pv[4];
        #pragma unroll
        for (int q = 0; q < 4; q++) pv[q] = proj[(size_t)(j0+jj+q)*256 + o];
        #pragma unroll
        for (int bb = 0; bb < 8; bb++) {
            const float4 vv = *(const float4*)&s_v[bb*256 + jj];
            acc[bb] = fmaf(vv.x, pv[0], acc[bb]);
            acc[bb] = fmaf(vv.y, pv[1], acc[bb]);
            acc[bb] = fmaf(vv.z, pv[2], acc[bb]);
            acc[bb] = fmaf(vv.w, pv[3], acc[bb]);
        }
    }
    #pragma unroll
    for (int bb = 0; bb < 8; bb++) atomicAdd(&outacc[bb*256 + o], acc[bb] * s_sc[bb]);
}

__global__ __launch_bounds__(256) void k_outnorm(
    const float* __restrict__ outacc, float* __restrict__ out)
{
    const int b = blockIdx.x, o = threadIdx.x;
    const float val = outacc[b*256 + o];
    float s = val*val;
    #pragma unroll
    for (int off = 32; off > 0; off >>= 1) s += __shfl_xor(s, off, 64);
    __shared__ float red[4];
    if ((o & 63) == 0) red[o >> 6] = s;
    __syncthreads();
    const float tot = red[0] + red[1] + red[2] + red[3];
    out[b*256 + o] = val / (sqrtf(tot) + 1e-12f);
}

// ---------------------------------------------------------------------------
extern "C" void kernel_launch(void* const* d_in, const int* in_sizes, int n_in,
                              void* d_out, int out_size, void* d_ws, size_t ws_size,
                              hipStream_t stream)
{
    (void)in_sizes; (void)n_in; (void)out_size; (void)ws_size;
    const float* x     = (const float*)d_in[0];
    const int*   m     = (const int*)  d_in[1];
    const float* pn_w1 = (const float*)d_in[2];
    const float* pn_b1 = (const float*)d_in[3];
    const float* pn_w2 = (const float*)d_in[4];
    const float* pn_b2 = (const float*)d_in[5];
    const float* kp    = (const float*)d_in[6];
    const float* bw1[3] = {(const float*)d_in[7],  (const float*)d_in[11], (const float*)d_in[15]};
    const float* bwk[3] = {(const float*)d_in[8],  (const float*)d_in[12], (const float*)d_in[16]};
    const float* bw2[3] = {(const float*)d_in[9],  (const float*)d_in[13], (const float*)d_in[17]};
    const float* bws[3] = {(const float*)d_in[10], (const float*)d_in[14], (const float*)d_in[18]};
    const float* vlad_wa      = (const float*)d_in[19];
    const float* vlad_centers = (const float*)d_in[20];
    const float* vlad_proj    = (const float*)d_in[21];
    float* out = (float*)d_out;

    char* ws = (char*)d_ws;
    size_t off = 0;
    auto alloc = [&](size_t bytes) -> void* {
        void* p = ws + off;
        off = (off + bytes + 255) & ~(size_t)255;
        return p;
    };
    float4* coords4 = (float4*)alloc((size_t)BN*16);
    float*  feat0   = (float*)alloc((size_t)BN*64*4);
    int*    idxb    = (int*)  alloc((size_t)BN*KNBR*4);
    float*  x1b     = (float*)alloc((size_t)BN*64*4);     // aliased by vpart later
    float*  fA      = (float*)alloc((size_t)BN*128*4);
    float*  fB      = (float*)alloc((size_t)BN*128*4);
    float*  abuf    = (float*)alloc((size_t)BN*64*4);
    float*  vbuf    = (float*)alloc((size_t)B*8192*4);
    float*  scaleb  = (float*)alloc((size_t)B*4);
    float*  sumA    = (float*)alloc((size_t)B*64*4);
    float*  outacc  = (float*)alloc((size_t)B*256*4);
    short*  wkT[3]  = {(short*)alloc(64*960*2), (short*)alloc(64*960*2), (short*)alloc(64*960*2)};
    short*  catT[3] = {(short*)alloc(128*192*2), (short*)alloc(128*192*2), (short*)alloc(128*192*2)};
    float*  vpart   = x1b;

    // weight prep (bf16 transposed copies; L2-resident)
    for (int l = 0; l < 3; l++)
        k_prep_wkT<<<(64*960 + 255)/256, 256, 0, stream>>>(bwk[l], wkT[l]);
    k_prep_catT<128><<<(128*128 + 255)/256, 256, 0, stream>>>(bw2[0], bws[0], catT[0]);
    k_prep_catT<192><<<(128*192 + 255)/256, 256, 0, stream>>>(bw2[1], bws[1], catT[1]);
    k_prep_catT<192><<<(128*192 + 255)/256, 256, 0, stream>>>(bw2[2], bws[2], catT[2]);

    k_zero<<<(B*64 + B*256 + 255)/256, 256, 0, stream>>>(sumA, B*64 + B*256);
    k_pointnet<<<BN/32, 256, 0, stream>>>(x, m, pn_w1, pn_b1, pn_w2, pn_b2, feat0, coords4);
    k_knn<<<BN/4, 256, 0, stream>>>(coords4, idxb);

    k_unary1<64> <<<BN/32, 256, 0, stream>>>(feat0, bw1[0], x1b);
    k_kpconv<64> <<<BN/8, 256, 0, stream>>>(x1b, coords4, kp, idxb, feat0, wkT[0], catT[0], fA);
    k_unary1<128><<<BN/32, 256, 0, stream>>>(fA, bw1[1], x1b);
    k_kpconv<128><<<BN/8, 256, 0, stream>>>(x1b, coords4, kp, idxb, fA, wkT[1], catT[1], fB);
    k_unary1<128><<<BN/32, 256, 0, stream>>>(fB, bw1[2], x1b);
    k_kpconv<128><<<BN/8, 256, 0, stream>>>(x1b, coords4, kp, idxb, fB, wkT[2], catT[2], fA);

    k_vlad_a<<<BN/32, 256, 0, stream>>>(fA, vlad_wa, m, abuf, sumA);
    k_vlad_acc<<<B*VCH, 256, 0, stream>>>(abuf, fA, vpart);
    k_vlad_norm<<<B*64, 128, 0, stream>>>(vpart, sumA, vlad_centers, vbuf);
    k_vnorm<<<B, 256, 0, stream>>>(vbuf, scaleb);
    k_proj<<<32, 256, 0, stream>>>(vbuf, scaleb, vlad_proj, outacc);
    k_outnorm<<<B, 256, 0, stream>>>(outacc, out);
}